// Round 1
// baseline (3662.389 us; speedup 1.0000x reference)
//
#include <hip/hip_runtime.h>
#include <math.h>

// Problem constants
#define BB 4
#define CC 64
#define C2 128
#define HH 128
#define WW 256
#define NN (BB*HH)          // 512 row-pairs
#define EPSBN 1e-5f

// ---------------------------------------------------------------------------
// K1: fused 1x1 conv (64->64) + concat + batchnorm.  out = bn(cat(conv(x), x))
// grid: (512) blocks = (b,h); 256 threads = w pixel
// ---------------------------------------------------------------------------
__global__ __launch_bounds__(256) void k_catbn(
    const float* __restrict__ x, const float* __restrict__ cw, const float* __restrict__ cb,
    const float* __restrict__ g, const float* __restrict__ bb_, const float* __restrict__ m,
    const float* __restrict__ v, float* __restrict__ out)
{
    int n = blockIdx.x; int b = n >> 7; int h = n & 127; int t = threadIdx.x;
    float xv[64];
#pragma unroll
    for (int i = 0; i < 64; ++i)
        xv[i] = x[(((b*64 + i)*128 + h) << 8) + t];
    for (int o = 0; o < 64; ++o) {
        float acc = cb[o];
#pragma unroll
        for (int i = 0; i < 64; ++i)
            acc = fmaf(cw[o*64 + i], xv[i], acc);
        float inv = rsqrtf(v[o] + EPSBN);
        out[(((b*128 + o)*128 + h) << 8) + t] = g[o]*(acc - m[o])*inv + bb_[o];
    }
#pragma unroll
    for (int o = 64; o < 128; ++o) {
        float inv = rsqrtf(v[o] + EPSBN);
        out[(((b*128 + o)*128 + h) << 8) + t] = g[o]*(xv[o-64] - m[o])*inv + bb_[o];
    }
}

// ---------------------------------------------------------------------------
// K2/K3: grouped 3x3 conv (4 groups of 32ch), pad=1. Optional leaky / residual.
// grid: (512 bh, 4 group, 2 wtile); 256 threads = 128 px * 2 oc-halves
// ---------------------------------------------------------------------------
template<bool LEAKY, bool RES>
__global__ __launch_bounds__(256) void k_conv3(
    const float* __restrict__ in, const float* __restrict__ wgt, const float* __restrict__ bias,
    const float* __restrict__ res, float* __restrict__ out)
{
    __shared__ float sm[32][3][132];
    int n = blockIdx.x; int b = n >> 7; int h = n & 127;
    int gg = blockIdx.y; int w0 = blockIdx.z * 128;
    int t = threadIdx.x;
    for (int idx = t; idx < 32*3*132; idx += 256) {
        int i = idx / 396; int rem = idx - i*396; int dy = rem / 132; int xx = rem - dy*132;
        int wg = w0 + xx - 1; int hg = h + dy - 1;
        float val = 0.f;
        if (xx < 130 && (unsigned)wg < 256u && (unsigned)hg < 128u)
            val = in[(((b*128 + gg*32 + i)*128 + hg) << 8) + wg];
        sm[i][dy][xx] = val;
    }
    __syncthreads();
    int px = t & 127; int oh = t >> 7;
    int ob = gg*32 + oh*16;
    float acc[16];
#pragma unroll
    for (int k = 0; k < 16; ++k) acc[k] = bias[ob + k];
    for (int i = 0; i < 32; ++i) {
#pragma unroll
        for (int dy = 0; dy < 3; ++dy) {
            float v0 = sm[i][dy][px], v1 = sm[i][dy][px+1], v2 = sm[i][dy][px+2];
            const float* wp = wgt + (ob*32 + i)*9 + dy*3;
#pragma unroll
            for (int k = 0; k < 16; ++k) {
                const float* wk = wp + k*288;   // (o stride) = 32*9
                acc[k] = fmaf(wk[0], v0, fmaf(wk[1], v1, fmaf(wk[2], v2, acc[k])));
            }
        }
    }
    int wout = w0 + px;
#pragma unroll
    for (int k = 0; k < 16; ++k) {
        int o = ob + k;
        float y = acc[k];
        if (LEAKY) y = y > 0.f ? y : 0.1f*y;
        int oi = (((b*128 + o)*128 + h) << 8) + wout;
        if (RES) y += res[oi];
        out[oi] = y;
    }
}

// ---------------------------------------------------------------------------
// K4: grouped 1x1 conv (128 -> 64, groups=2)
// grid: (512 bh, 2 group); 256 threads = w pixel
// ---------------------------------------------------------------------------
__global__ __launch_bounds__(256) void k_conv1x1g2(
    const float* __restrict__ in, const float* __restrict__ wgt, const float* __restrict__ bias,
    float* __restrict__ out)
{
    int n = blockIdx.x; int b = n >> 7; int h = n & 127;
    int gg = blockIdx.y; int t = threadIdx.x;
    float rv[64];
#pragma unroll
    for (int i = 0; i < 64; ++i)
        rv[i] = in[(((b*128 + gg*64 + i)*128 + h) << 8) + t];
    for (int ol = 0; ol < 32; ++ol) {
        int o = gg*32 + ol;
        float acc = bias[o];
#pragma unroll
        for (int i = 0; i < 64; ++i)
            acc = fmaf(wgt[o*64 + i], rv[i], acc);
        out[(((b*64 + o)*128 + h) << 8) + t] = acc;
    }
}

// ---------------------------------------------------------------------------
// K5: subtract row mean over w.  grid: 32768 rows (b*c*h); 256 threads
// ---------------------------------------------------------------------------
__global__ __launch_bounds__(256) void k_meansub(float* __restrict__ buf)
{
    int row = blockIdx.x; int t = threadIdx.x;
    float vv = buf[row*256 + t];
    float s = vv;
#pragma unroll
    for (int off = 32; off > 0; off >>= 1) s += __shfl_xor(s, off);
    __shared__ float red[4];
    int lane = t & 63, wid = t >> 6;
    if (lane == 0) red[wid] = s;
    __syncthreads();
    s = red[0] + red[1] + red[2] + red[3];
    buf[row*256 + t] = vv - s*(1.0f/256.0f);
}

// ---------------------------------------------------------------------------
// K6: score S[n,i,j] = sum_c Q[b,c,h,i]*K[b,c,h,j]
// grid: (512 n, 4 itile, 2 jtile); 256 threads; thread tile 4i x 8j
// ---------------------------------------------------------------------------
__global__ __launch_bounds__(256) void k_score(
    const float* __restrict__ Q, const float* __restrict__ Km, float* __restrict__ S)
{
    __shared__ float Qs[64][68];
    __shared__ float Ks[64][132];
    int n = blockIdx.x; int b = n >> 7; int h = n & 127;
    int i0 = blockIdx.y*64, j0 = blockIdx.z*128;
    int t = threadIdx.x;
    for (int idx = t; idx < 64*64; idx += 256) {
        int c = idx >> 6, ii = idx & 63;
        Qs[c][ii] = Q[(((b*64 + c)*128 + h) << 8) + i0 + ii];
    }
    for (int idx = t; idx < 64*128; idx += 256) {
        int c = idx >> 7, jj = idx & 127;
        Ks[c][jj] = Km[(((b*64 + c)*128 + h) << 8) + j0 + jj];
    }
    __syncthreads();
    int jg = t & 15, ig = t >> 4;
    int ii = ig*4, jj = jg*8;
    float acc[4][8];
#pragma unroll
    for (int a = 0; a < 4; ++a)
#pragma unroll
        for (int q = 0; q < 8; ++q) acc[a][q] = 0.f;
    for (int c = 0; c < 64; ++c) {
        float qa[4]; *(float4*)qa = *(const float4*)&Qs[c][ii];
        float ka[8];
        *(float4*)&ka[0] = *(const float4*)&Ks[c][jj];
        *(float4*)&ka[4] = *(const float4*)&Ks[c][jj+4];
#pragma unroll
        for (int a = 0; a < 4; ++a)
#pragma unroll
            for (int q = 0; q < 8; ++q)
                acc[a][q] = fmaf(qa[a], ka[q], acc[a][q]);
    }
#pragma unroll
    for (int a = 0; a < 4; ++a) {
        size_t base = ((size_t)n << 16) + (size_t)(i0 + ii + a)*256 + j0 + jj;
        *(float4*)&S[base]   = *(float4*)&acc[a][0];
        *(float4*)&S[base+4] = *(float4*)&acc[a][4];
    }
}

// ---------------------------------------------------------------------------
// K7: row softmax stats (max over j, inv sum of exp). grid (256 i, 512 n)
// ---------------------------------------------------------------------------
__global__ __launch_bounds__(256) void k_rowstats(
    const float* __restrict__ S, float* __restrict__ rmax, float* __restrict__ rsumi)
{
    int i = blockIdx.x, n = blockIdx.y, t = threadIdx.x;
    float vv = S[((size_t)n << 16) + (i << 8) + t];
    float mx = vv;
#pragma unroll
    for (int off = 32; off > 0; off >>= 1) mx = fmaxf(mx, __shfl_xor(mx, off));
    __shared__ float red[4]; __shared__ float red2[4];
    int lane = t & 63, wid = t >> 6;
    if (lane == 0) red[wid] = mx;
    __syncthreads();
    mx = fmaxf(fmaxf(red[0], red[1]), fmaxf(red[2], red[3]));
    float e = __expf(vv - mx);
#pragma unroll
    for (int off = 32; off > 0; off >>= 1) e += __shfl_xor(e, off);
    if (lane == 0) red2[wid] = e;
    __syncthreads();
    if (t == 0) {
        float s = red2[0] + red2[1] + red2[2] + red2[3];
        rmax[n*256 + i] = mx;
        rsumi[n*256 + i] = 1.0f / s;
    }
}

// ---------------------------------------------------------------------------
// K8: column softmax stats via online max/sum. grid (512 n); thread = column j
// ---------------------------------------------------------------------------
__global__ __launch_bounds__(256) void k_colstats(
    const float* __restrict__ S, float* __restrict__ cmax, float* __restrict__ csumi)
{
    int n = blockIdx.x; int t = threadIdx.x;
    float m = -1e30f, s = 0.f;
    for (int i = 0; i < 256; ++i) {
        float vv = S[((size_t)n << 16) + (i << 8) + t];
        float nm = fmaxf(m, vv);
        s = s*__expf(m - nm) + __expf(vv - nm);
        m = nm;
    }
    cmax[n*256 + t] = m;
    csumi[n*256 + t] = 1.0f / s;
}

// ---------------------------------------------------------------------------
// K9: V_l[n,i] = sum_j (sum_d M_r2l[n,i+d,j]) * M_l2r[n,j,i]
// grid (256 i, 512 n); threads j; block-reduce
// ---------------------------------------------------------------------------
__global__ __launch_bounds__(256) void k_vl(
    const float* __restrict__ S, const float* __restrict__ rmax, const float* __restrict__ rsumi,
    const float* __restrict__ cmax, const float* __restrict__ csumi, float* __restrict__ Vl)
{
    int i = blockIdx.x, n = blockIdx.y, t = threadIdx.x;
    const float* Sp = S + ((size_t)n << 16);
    float relaxed = 0.f;
#pragma unroll
    for (int d = -2; d <= 2; ++d) {
        int r = i + d;
        if ((unsigned)r < 256u)
            relaxed += __expf(Sp[(r << 8) + t] - rmax[n*256 + r]) * rsumi[n*256 + r];
    }
    float ml2r = __expf(Sp[(i << 8) + t] - cmax[n*256 + t]) * csumi[n*256 + t];
    float p = relaxed * ml2r;
#pragma unroll
    for (int off = 32; off > 0; off >>= 1) p += __shfl_xor(p, off);
    __shared__ float red[4];
    int lane = t & 63, wid = t >> 6;
    if (lane == 0) red[wid] = p;
    __syncthreads();
    if (t == 0) Vl[n*256 + i] = red[0] + red[1] + red[2] + red[3];
}

// ---------------------------------------------------------------------------
// K10: V_r[n,i] = sum_j (sum_d M_l2r[n,i+d,j]) * M_r2l[n,j,i]
// grid (512 n); thread = i; loop over rows j with LDS row buffer
// ---------------------------------------------------------------------------
__global__ __launch_bounds__(256) void k_vr(
    const float* __restrict__ S, const float* __restrict__ rmax, const float* __restrict__ rsumi,
    const float* __restrict__ cmax, const float* __restrict__ csumi, float* __restrict__ Vr)
{
    __shared__ float row[260];
    int n = blockIdx.x, t = threadIdx.x;
    if (t < 2) { row[t] = 0.f; row[258 + t] = 0.f; }
    float cm[5], ci[5];
#pragma unroll
    for (int d = 0; d < 5; ++d) {
        int idx = t + d - 2;
        if ((unsigned)idx < 256u) { cm[d] = cmax[n*256 + idx]; ci[d] = csumi[n*256 + idx]; }
        else { cm[d] = 0.f; ci[d] = 0.f; }
    }
    float acc = 0.f;
    const float* Sp = S + ((size_t)n << 16);
    for (int j = 0; j < 256; ++j) {
        __syncthreads();
        row[2 + t] = Sp[(j << 8) + t];
        __syncthreads();
        float relax = 0.f;
#pragma unroll
        for (int d = 0; d < 5; ++d)
            relax += __expf(row[t + d] - cm[d]) * ci[d];
        float mr2l = __expf(row[2 + t] - rmax[n*256 + j]) * rsumi[n*256 + j];
        acc = fmaf(relax, mr2l, acc);
    }
    Vr[n*256 + t] = acc;
}

// ---------------------------------------------------------------------------
// K11L: x_lT = M_r2l @ xr ; out_left = x_left*(1-t) + x_lT*t, t=tanh(5 V_l)
// grid (512 n, 4 itile); 256 threads; thread tile 4i x 4cc
// ---------------------------------------------------------------------------
__global__ __launch_bounds__(256) void k_outleft(
    const float* __restrict__ S, const float* __restrict__ rmax, const float* __restrict__ rsumi,
    const float* __restrict__ Vl, const float* __restrict__ x_left, const float* __restrict__ x_right,
    float* __restrict__ out)
{
    __shared__ float Ms[64][68];   // [j'][i']
    __shared__ float Xs[64][69];   // [cc][j']
    int n = blockIdx.x; int b = n >> 7; int h = n & 127;
    int i0 = blockIdx.y*64;
    int t = threadIdx.x;
    int cg = t & 15, ig = t >> 4;
    int cc0 = cg*4, ii0 = ig*4;
    float acc[4][4] = {};
    for (int chunk = 0; chunk < 4; ++chunk) {
        int jc = chunk*64;
        __syncthreads();
        for (int idx = t; idx < 4096; idx += 256) {
            int jj = idx & 63, ii = idx >> 6;
            float mval = __expf(S[((size_t)n << 16) + (size_t)(i0 + ii)*256 + jc + jj]
                                - rmax[n*256 + i0 + ii]) * rsumi[n*256 + i0 + ii];
            Ms[jj][ii] = mval;
        }
        for (int idx = t; idx < 4096; idx += 256) {
            int jj = idx & 63, cc = idx >> 6;
            Xs[cc][jj] = x_right[(((b*64 + cc)*128 + h) << 8) + jc + jj];
        }
        __syncthreads();
        for (int j = 0; j < 64; ++j) {
            float m4[4]; *(float4*)m4 = *(const float4*)&Ms[j][ii0];
            float xv[4];
#pragma unroll
            for (int q = 0; q < 4; ++q) xv[q] = Xs[cc0 + q][j];
#pragma unroll
            for (int a = 0; a < 4; ++a)
#pragma unroll
                for (int q = 0; q < 4; ++q)
                    acc[a][q] = fmaf(m4[a], xv[q], acc[a][q]);
        }
    }
    float vl4[4]; *(float4*)vl4 = *(const float4*)&Vl[n*256 + i0 + ii0];
    float tv[4];
#pragma unroll
    for (int a = 0; a < 4; ++a) tv[a] = tanhf(5.f*vl4[a]);
#pragma unroll
    for (int q = 0; q < 4; ++q) {
        size_t base = (((size_t)(b*64 + cc0 + q)*128 + h) << 8) + i0 + ii0;
        float xl[4]; *(float4*)xl = *(const float4*)&x_left[base];
        float o4[4];
#pragma unroll
        for (int a = 0; a < 4; ++a)
            o4[a] = xl[a]*(1.f - tv[a]) + acc[a][q]*tv[a];
        *(float4*)&out[base] = *(float4*)o4;
    }
}

// ---------------------------------------------------------------------------
// K11R: x_rT = M_l2r @ xl ; out_right = x_right*(1-t) + x_rT*t, t=tanh(5 V_r)
// grid (512 n, 4 jtile); thread tile 4jq x 4cc
// ---------------------------------------------------------------------------
__global__ __launch_bounds__(256) void k_outright(
    const float* __restrict__ S, const float* __restrict__ cmax, const float* __restrict__ csumi,
    const float* __restrict__ Vr, const float* __restrict__ x_left, const float* __restrict__ x_right,
    float* __restrict__ out)
{
    __shared__ float Ms[64][68];   // [i'][jq']
    __shared__ float Xs[64][69];   // [cc][i']
    int n = blockIdx.x; int b = n >> 7; int h = n & 127;
    int j0 = blockIdx.y*64;
    int t = threadIdx.x;
    int cg = t & 15, jg = t >> 4;
    int cc0 = cg*4, jj0 = jg*4;
    float acc[4][4] = {};
    for (int chunk = 0; chunk < 4; ++chunk) {
        int ic = chunk*64;
        __syncthreads();
        for (int idx = t; idx < 4096; idx += 256) {
            int jj = idx & 63, ii = idx >> 6;
            float mval = __expf(S[((size_t)n << 16) + (size_t)(ic + ii)*256 + j0 + jj]
                                - cmax[n*256 + j0 + jj]) * csumi[n*256 + j0 + jj];
            Ms[ii][jj] = mval;
        }
        for (int idx = t; idx < 4096; idx += 256) {
            int ii = idx & 63, cc = idx >> 6;
            Xs[cc][ii] = x_left[(((b*64 + cc)*128 + h) << 8) + ic + ii];
        }
        __syncthreads();
        for (int i = 0; i < 64; ++i) {
            float m4[4]; *(float4*)m4 = *(const float4*)&Ms[i][jj0];
            float xv[4];
#pragma unroll
            for (int q = 0; q < 4; ++q) xv[q] = Xs[cc0 + q][i];
#pragma unroll
            for (int a = 0; a < 4; ++a)
#pragma unroll
                for (int q = 0; q < 4; ++q)
                    acc[a][q] = fmaf(m4[a], xv[q], acc[a][q]);
        }
    }
    float vr4[4]; *(float4*)vr4 = *(const float4*)&Vr[n*256 + j0 + jj0];
    float tv[4];
#pragma unroll
    for (int a = 0; a < 4; ++a) tv[a] = tanhf(5.f*vr4[a]);
#pragma unroll
    for (int q = 0; q < 4; ++q) {
        size_t base = (((size_t)(b*64 + cc0 + q)*128 + h) << 8) + j0 + jj0;
        float xr[4]; *(float4*)xr = *(const float4*)&x_right[base];
        float o4[4];
#pragma unroll
        for (int a = 0; a < 4; ++a)
            o4[a] = xr[a]*(1.f - tv[a]) + acc[a][q]*tv[a];
        *(float4*)&out[base] = *(float4*)o4;
    }
}

// ---------------------------------------------------------------------------
extern "C" void kernel_launch(void* const* d_in, const int* in_sizes, int n_in,
                              void* d_out, int out_size, void* d_ws, size_t ws_size,
                              hipStream_t stream)
{
    const float* x_left  = (const float*)d_in[0];
    const float* x_right = (const float*)d_in[1];
    const float* conv1_w = (const float*)d_in[2];
    const float* conv1_b = (const float*)d_in[3];
    const float* conv2_w = (const float*)d_in[4];
    const float* conv2_b = (const float*)d_in[5];
    const float* bn_g    = (const float*)d_in[6];
    const float* bn_b    = (const float*)d_in[7];
    const float* bn_m    = (const float*)d_in[8];
    const float* bn_v    = (const float*)d_in[9];
    const float* rb_w1   = (const float*)d_in[10];
    const float* rb_b1   = (const float*)d_in[11];
    const float* rb_w2   = (const float*)d_in[12];
    const float* rb_b2   = (const float*)d_in[13];
    const float* bq_w    = (const float*)d_in[14];
    const float* bq_b    = (const float*)d_in[15];
    const float* bs_w    = (const float*)d_in[16];
    const float* bs_b    = (const float*)d_in[17];

    float* ws = (float*)d_ws;
    // Workspace layout (floats). S (134MB) aliases A+B which are dead by then.
    float* A     = ws;                    // 16,777,216  (u / r buffer)
    float* Bf    = ws + 16777216;         // 16,777,216  (y1 buffer)
    float* S     = ws;                    // 33,554,432  (score, aliases A+B)
    float* Qb    = ws + 33554432;         //  8,388,608
    float* Kb    = ws + 41943040;         //  8,388,608
    float* rmax  = ws + 50331648;         //    131,072
    float* rsumi = ws + 50462720;         //    131,072
    float* cmax  = ws + 50593792;         //    131,072
    float* csumi = ws + 50724864;         //    131,072
    float* Vl    = ws + 50855936;         //    131,072
    float* Vr    = ws + 50987008;         //    131,072

    float* out_left  = (float*)d_out;
    float* out_right = (float*)d_out + 8388608;

    // ---- left branch -> Q ----
    k_catbn<<<NN, 256, 0, stream>>>(x_left, conv1_w, conv1_b, bn_g, bn_b, bn_m, bn_v, A);
    k_conv3<true,  false><<<dim3(NN, 4, 2), 256, 0, stream>>>(A, rb_w1, rb_b1, nullptr, Bf);
    k_conv3<false, true ><<<dim3(NN, 4, 2), 256, 0, stream>>>(Bf, rb_w2, rb_b2, A, A);
    k_conv1x1g2<<<dim3(NN, 2), 256, 0, stream>>>(A, bq_w, bq_b, Qb);
    k_meansub<<<BB*CC*HH, 256, 0, stream>>>(Qb);

    // ---- right branch -> K ----
    k_catbn<<<NN, 256, 0, stream>>>(x_right, conv2_w, conv2_b, bn_g, bn_b, bn_m, bn_v, A);
    k_conv3<true,  false><<<dim3(NN, 4, 2), 256, 0, stream>>>(A, rb_w1, rb_b1, nullptr, Bf);
    k_conv3<false, true ><<<dim3(NN, 4, 2), 256, 0, stream>>>(Bf, rb_w2, rb_b2, A, A);
    k_conv1x1g2<<<dim3(NN, 2), 256, 0, stream>>>(A, bs_w, bs_b, Kb);
    k_meansub<<<BB*CC*HH, 256, 0, stream>>>(Kb);

    // ---- attention ----
    k_score<<<dim3(NN, 4, 2), 256, 0, stream>>>(Qb, Kb, S);
    k_rowstats<<<dim3(256, NN), 256, 0, stream>>>(S, rmax, rsumi);
    k_colstats<<<NN, 256, 0, stream>>>(S, cmax, csumi);
    k_vl<<<dim3(256, NN), 256, 0, stream>>>(S, rmax, rsumi, cmax, csumi, Vl);
    k_vr<<<NN, 256, 0, stream>>>(S, rmax, rsumi, cmax, csumi, Vr);
    k_outleft<<<dim3(NN, 4), 256, 0, stream>>>(S, rmax, rsumi, Vl, x_left, x_right, out_left);
    k_outright<<<dim3(NN, 4), 256, 0, stream>>>(S, cmax, csumi, Vr, x_left, x_right, out_right);
}

// Round 2
// 1367.810 us; speedup vs baseline: 2.6776x; 2.6776x over previous
//
#include <hip/hip_runtime.h>
#include <hip/hip_bf16.h>
#include <math.h>

// Problem constants
#define BB 4
#define CC 64
#define C2 128
#define HH 128
#define WW 256
#define NN (BB*HH)          // 512 row-pairs
#define EPSBN 1e-5f

typedef __attribute__((ext_vector_type(8))) short short8;
typedef __attribute__((ext_vector_type(4))) float f32x4;

__device__ inline unsigned short bf16bits(float x) {
    __hip_bfloat16 h = __float2bfloat16(x);
    union { __hip_bfloat16 h; unsigned short u; } c; c.h = h; return c.u;
}
__device__ inline float bf16tof(unsigned short u) {
    union { unsigned short u; __hip_bfloat16 h; } c; c.u = u; return __bfloat162float(c.h);
}

// ---------------------------------------------------------------------------
// K1: fused 1x1 conv (64->64) + concat + batchnorm -> u  (channel-last bf16)
// u[b][h][w][128].  grid: 512 = (b,h); 256 threads = w pixel.  fp32 VALU math,
// weights staged in LDS (broadcast reads), BN folded into scale/offset.
// ---------------------------------------------------------------------------
__global__ __launch_bounds__(256) void k_catbn(
    const float* __restrict__ x, const float* __restrict__ cw, const float* __restrict__ cb,
    const float* __restrict__ g, const float* __restrict__ bb_, const float* __restrict__ m,
    const float* __restrict__ v, __hip_bfloat16* __restrict__ u)
{
    __shared__ float Wl[64][68];
    __shared__ float sS[64], sT[64], sS2[64], sT2[64];
    int n = blockIdx.x; int b = n >> 7; int h = n & 127; int t = threadIdx.x;
    for (int idx = t; idx < 4096; idx += 256) Wl[idx >> 6][idx & 63] = cw[idx];
    if (t < 64) {
        float inv = rsqrtf(v[t] + EPSBN); float s = g[t] * inv;
        sS[t] = s; sT[t] = bb_[t] + s * (cb[t] - m[t]);
        float inv2 = rsqrtf(v[t + 64] + EPSBN); float s2 = g[t + 64] * inv2;
        sS2[t] = s2; sT2[t] = bb_[t + 64] - s2 * m[t + 64];
    }
    float xv[64];
#pragma unroll
    for (int i = 0; i < 64; ++i)
        xv[i] = x[(((b*64 + i)*128 + h) << 8) + t];
    __syncthreads();
    __hip_bfloat16* up = u + ((size_t)((b*128 + h)*256 + t)) * 128;
    for (int o8 = 0; o8 < 8; ++o8) {
        union { __hip_bfloat16 h[8]; uint4 v4; } pk;
#pragma unroll
        for (int oo = 0; oo < 8; ++oo) {
            int o = o8*8 + oo;
            float acc = 0.f;
#pragma unroll
            for (int i4 = 0; i4 < 16; ++i4) {
                float4 w4 = *(const float4*)&Wl[o][i4*4];
                acc = fmaf(w4.x, xv[i4*4+0], acc);
                acc = fmaf(w4.y, xv[i4*4+1], acc);
                acc = fmaf(w4.z, xv[i4*4+2], acc);
                acc = fmaf(w4.w, xv[i4*4+3], acc);
            }
            pk.h[oo] = __float2bfloat16(sS[o]*acc + sT[o]);
        }
        *(uint4*)(up + o8*8) = pk.v4;
    }
    for (int o8 = 0; o8 < 8; ++o8) {
        union { __hip_bfloat16 h[8]; uint4 v4; } pk;
#pragma unroll
        for (int oo = 0; oo < 8; ++oo) {
            int i = o8*8 + oo;
            pk.h[oo] = __float2bfloat16(sS2[i]*xv[i] + sT2[i]);
        }
        *(uint4*)(up + 64 + o8*8) = pk.v4;
    }
}

// ---------------------------------------------------------------------------
// K2/K3: grouped 3x3 conv via implicit-GEMM bf16 MFMA 16x16x32.
// In/out channel-last bf16 [b][h][w][128].  K reordered: k=(ky*3+kx)*32+ic.
// grid (512 bh, 4 group, 2 wtile); 256 thr = 4 waves; wave: 32px x 32oc.
// ---------------------------------------------------------------------------
template<bool LEAKY, bool RES>
__global__ __launch_bounds__(256) void k_conv3m(
    const __hip_bfloat16* __restrict__ in, const float* __restrict__ wgt,
    const float* __restrict__ bias, const __hip_bfloat16* __restrict__ res,
    __hip_bfloat16* __restrict__ out)
{
    __shared__ __hip_bfloat16 Wl[32*296];    // [mo][k] stride 296 (2-way free)
    __shared__ __hip_bfloat16 Xl[3*130*40];  // [row][px][ic] px-stride 40 (2-way free)
    int n = blockIdx.x; int b = n >> 7; int h = n & 127;
    int g = blockIdx.y; int w0 = blockIdx.z * 128;
    int t = threadIdx.x;
    // ---- stage weights (fp32 -> bf16, reordered) ----
    for (int p = t; p < 4608; p += 256) {
        int kidx = p * 2;
        int mo = kidx / 288; int kr = kidx - mo*288;
        int ic = kr & 31; int ks = kr >> 5;
        int gb = ((g*32 + mo)*32 + ic)*9 + ks;
        union { __hip_bfloat16 h[2]; unsigned int u; } pr;
        pr.h[0] = __float2bfloat16(wgt[gb]);
        pr.h[1] = __float2bfloat16(wgt[gb + 9]);   // ic+1, same (ky,kx)
        *(unsigned int*)&Wl[mo*296 + kr] = pr.u;
    }
    // ---- stage input tile (3 rows x 130 px x 32 ic) ----
    for (int idx = t; idx < 1560; idx += 256) {
        int r = idx / 520; int rem = idx - r*520; int p = rem >> 2; int q = rem & 3;
        int hr = h + r - 1; int wg = w0 + p - 1;
        uint4 val = make_uint4(0,0,0,0);
        if ((unsigned)hr < 128u && (unsigned)wg < 256u)
            val = *(const uint4*)(in + ((size_t)((b*128 + hr)*256 + wg))*128 + g*32 + q*8);
        *(uint4*)&Xl[(r*130 + p)*40 + q*8] = val;
    }
    __syncthreads();
    int lane = t & 63, wv = t >> 6;
    int m16 = lane & 15, quad = lane >> 4;
    f32x4 acc[2][2] = {};
#pragma unroll
    for (int ks = 0; ks < 9; ++ks) {
        int ky = ks / 3, kx = ks - ky*3;
        short8 af0 = *(const short8*)&Wl[m16*296 + ks*32 + quad*8];
        short8 af1 = *(const short8*)&Wl[(16 + m16)*296 + ks*32 + quad*8];
        int px0 = wv*32 + m16;
        short8 bf0 = *(const short8*)&Xl[(ky*130 + px0 + kx)*40 + quad*8];
        short8 bf1 = *(const short8*)&Xl[(ky*130 + px0 + 16 + kx)*40 + quad*8];
        acc[0][0] = __builtin_amdgcn_mfma_f32_16x16x32_bf16(af0, bf0, acc[0][0], 0, 0, 0);
        acc[0][1] = __builtin_amdgcn_mfma_f32_16x16x32_bf16(af0, bf1, acc[0][1], 0, 0, 0);
        acc[1][0] = __builtin_amdgcn_mfma_f32_16x16x32_bf16(af1, bf0, acc[1][0], 0, 0, 0);
        acc[1][1] = __builtin_amdgcn_mfma_f32_16x16x32_bf16(af1, bf1, acc[1][1], 0, 0, 0);
    }
    // ---- epilogue: bias (+leaky) (+residual), write channel-last bf16 ----
    float bo[2][4];
#pragma unroll
    for (int mt = 0; mt < 2; ++mt)
#pragma unroll
        for (int r = 0; r < 4; ++r)
            bo[mt][r] = bias[g*32 + mt*16 + quad*4 + r];
#pragma unroll
    for (int mt = 0; mt < 2; ++mt)
#pragma unroll
        for (int nt = 0; nt < 2; ++nt) {
            int px = w0 + wv*32 + nt*16 + m16;
            int oc = g*32 + mt*16 + quad*4;
            size_t off = ((size_t)((b*128 + h)*256 + px))*128 + oc;
            float rv4[4] = {0.f, 0.f, 0.f, 0.f};
            if (RES) {
                union { unsigned int u2[2]; __hip_bfloat16 h[4]; uint2 v2; } rr;
                rr.v2 = *(const uint2*)(res + off);
#pragma unroll
                for (int r = 0; r < 4; ++r) rv4[r] = __bfloat162float(rr.h[r]);
            }
            union { __hip_bfloat16 h[4]; uint2 v2; } ov;
#pragma unroll
            for (int r = 0; r < 4; ++r) {
                float y = acc[mt][nt][r] + bo[mt][r];
                if (LEAKY) y = y > 0.f ? y : 0.1f*y;
                if (RES) y += rv4[r];
                ov.h[r] = __float2bfloat16(y);
            }
            *(uint2*)(out + off) = ov.v2;
        }
}

// ---------------------------------------------------------------------------
// K4: grouped 1x1 conv (128 -> 64, groups=2), bf16 channel-last in, fp32
// planar out.  Weights in LDS (broadcast reads). grid (512 bh, 2 group).
// ---------------------------------------------------------------------------
__global__ __launch_bounds__(256) void k_conv1x1g2(
    const __hip_bfloat16* __restrict__ in, const float* __restrict__ wgt,
    const float* __restrict__ bias, float* __restrict__ out)
{
    __shared__ float Wl[32][68];
    int n = blockIdx.x; int b = n >> 7; int h = n & 127;
    int g = blockIdx.y; int t = threadIdx.x;
    for (int idx = t; idx < 2048; idx += 256) Wl[idx >> 6][idx & 63] = wgt[g*2048 + idx];
    float rv[64];
    const __hip_bfloat16* rp = in + ((size_t)((b*128 + h)*256 + t))*128 + g*64;
    for (int i8 = 0; i8 < 8; ++i8) {
        union { uint4 v4; __hip_bfloat16 h[8]; } ld;
        ld.v4 = *(const uint4*)(rp + i8*8);
#pragma unroll
        for (int j = 0; j < 8; ++j) rv[i8*8 + j] = __bfloat162float(ld.h[j]);
    }
    __syncthreads();
    for (int ol = 0; ol < 32; ++ol) {
        float acc = bias[g*32 + ol];
#pragma unroll
        for (int i4 = 0; i4 < 16; ++i4) {
            float4 w4 = *(const float4*)&Wl[ol][i4*4];
            acc = fmaf(w4.x, rv[i4*4+0], acc);
            acc = fmaf(w4.y, rv[i4*4+1], acc);
            acc = fmaf(w4.z, rv[i4*4+2], acc);
            acc = fmaf(w4.w, rv[i4*4+3], acc);
        }
        out[(((b*64 + g*32 + ol)*128 + h) << 8) + t] = acc;
    }
}

// ---------------------------------------------------------------------------
// K5: subtract row mean over w.  grid: 32768 rows (b*c*h); 256 threads
// ---------------------------------------------------------------------------
__global__ __launch_bounds__(256) void k_meansub(float* __restrict__ buf)
{
    int row = blockIdx.x; int t = threadIdx.x;
    float vv = buf[row*256 + t];
    float s = vv;
#pragma unroll
    for (int off = 32; off > 0; off >>= 1) s += __shfl_xor(s, off);
    __shared__ float red[4];
    int lane = t & 63, wid = t >> 6;
    if (lane == 0) red[wid] = s;
    __syncthreads();
    s = red[0] + red[1] + red[2] + red[3];
    buf[row*256 + t] = vv - s*(1.0f/256.0f);
}

// ---------------------------------------------------------------------------
// K6: score S[n,i,j] = sum_c Q[b,c,h,i]*K[b,c,h,j]
// grid: (512 n, 4 itile, 2 jtile); 256 threads; thread tile 4i x 8j
// ---------------------------------------------------------------------------
__global__ __launch_bounds__(256) void k_score(
    const float* __restrict__ Q, const float* __restrict__ Km, float* __restrict__ S)
{
    __shared__ float Qs[64][68];
    __shared__ float Ks[64][132];
    int n = blockIdx.x; int b = n >> 7; int h = n & 127;
    int i0 = blockIdx.y*64, j0 = blockIdx.z*128;
    int t = threadIdx.x;
    for (int idx = t; idx < 64*64; idx += 256) {
        int c = idx >> 6, ii = idx & 63;
        Qs[c][ii] = Q[(((b*64 + c)*128 + h) << 8) + i0 + ii];
    }
    for (int idx = t; idx < 64*128; idx += 256) {
        int c = idx >> 7, jj = idx & 127;
        Ks[c][jj] = Km[(((b*64 + c)*128 + h) << 8) + j0 + jj];
    }
    __syncthreads();
    int jg = t & 15, ig = t >> 4;
    int ii = ig*4, jj = jg*8;
    float acc[4][8];
#pragma unroll
    for (int a = 0; a < 4; ++a)
#pragma unroll
        for (int q = 0; q < 8; ++q) acc[a][q] = 0.f;
    for (int c = 0; c < 64; ++c) {
        float qa[4]; *(float4*)qa = *(const float4*)&Qs[c][ii];
        float ka[8];
        *(float4*)&ka[0] = *(const float4*)&Ks[c][jj];
        *(float4*)&ka[4] = *(const float4*)&Ks[c][jj+4];
#pragma unroll
        for (int a = 0; a < 4; ++a)
#pragma unroll
            for (int q = 0; q < 8; ++q)
                acc[a][q] = fmaf(qa[a], ka[q], acc[a][q]);
    }
#pragma unroll
    for (int a = 0; a < 4; ++a) {
        size_t base = ((size_t)n << 16) + (size_t)(i0 + ii + a)*256 + j0 + jj;
        *(float4*)&S[base]   = *(float4*)&acc[a][0];
        *(float4*)&S[base+4] = *(float4*)&acc[a][4];
    }
}

// ---------------------------------------------------------------------------
// K7: row softmax stats (max over j, inv sum of exp). grid (256 i, 512 n)
// ---------------------------------------------------------------------------
__global__ __launch_bounds__(256) void k_rowstats(
    const float* __restrict__ S, float* __restrict__ rmax, float* __restrict__ rsumi)
{
    int i = blockIdx.x, n = blockIdx.y, t = threadIdx.x;
    float vv = S[((size_t)n << 16) + (i << 8) + t];
    float mx = vv;
#pragma unroll
    for (int off = 32; off > 0; off >>= 1) mx = fmaxf(mx, __shfl_xor(mx, off));
    __shared__ float red[4]; __shared__ float red2[4];
    int lane = t & 63, wid = t >> 6;
    if (lane == 0) red[wid] = mx;
    __syncthreads();
    mx = fmaxf(fmaxf(red[0], red[1]), fmaxf(red[2], red[3]));
    float e = __expf(vv - mx);
#pragma unroll
    for (int off = 32; off > 0; off >>= 1) e += __shfl_xor(e, off);
    if (lane == 0) red2[wid] = e;
    __syncthreads();
    if (t == 0) {
        float s = red2[0] + red2[1] + red2[2] + red2[3];
        rmax[n*256 + i] = mx;
        rsumi[n*256 + i] = 1.0f / s;
    }
}

// ---------------------------------------------------------------------------
// K8: column softmax stats via online max/sum. grid (512 n); thread = column j
// ---------------------------------------------------------------------------
__global__ __launch_bounds__(256) void k_colstats(
    const float* __restrict__ S, float* __restrict__ cmax, float* __restrict__ csumi)
{
    int n = blockIdx.x; int t = threadIdx.x;
    float m = -1e30f, s = 0.f;
    for (int i = 0; i < 256; ++i) {
        float vv = S[((size_t)n << 16) + (i << 8) + t];
        float nm = fmaxf(m, vv);
        s = s*__expf(m - nm) + __expf(vv - nm);
        m = nm;
    }
    cmax[n*256 + t] = m;
    csumi[n*256 + t] = 1.0f / s;
}

// ---------------------------------------------------------------------------
// K9: V_l[n,i] = sum_j (sum_d M_r2l[n,i+d,j]) * M_l2r[n,j,i]
// ---------------------------------------------------------------------------
__global__ __launch_bounds__(256) void k_vl(
    const float* __restrict__ S, const float* __restrict__ rmax, const float* __restrict__ rsumi,
    const float* __restrict__ cmax, const float* __restrict__ csumi, float* __restrict__ Vl)
{
    int i = blockIdx.x, n = blockIdx.y, t = threadIdx.x;
    const float* Sp = S + ((size_t)n << 16);
    float relaxed = 0.f;
#pragma unroll
    for (int d = -2; d <= 2; ++d) {
        int r = i + d;
        if ((unsigned)r < 256u)
            relaxed += __expf(Sp[(r << 8) + t] - rmax[n*256 + r]) * rsumi[n*256 + r];
    }
    float ml2r = __expf(Sp[(i << 8) + t] - cmax[n*256 + t]) * csumi[n*256 + t];
    float p = relaxed * ml2r;
#pragma unroll
    for (int off = 32; off > 0; off >>= 1) p += __shfl_xor(p, off);
    __shared__ float red[4];
    int lane = t & 63, wid = t >> 6;
    if (lane == 0) red[wid] = p;
    __syncthreads();
    if (t == 0) Vl[n*256 + i] = red[0] + red[1] + red[2] + red[3];
}

// ---------------------------------------------------------------------------
// K10: V_r[n,i] = sum_j (sum_d M_l2r[n,i+d,j]) * M_r2l[n,j,i]
// ---------------------------------------------------------------------------
__global__ __launch_bounds__(256) void k_vr(
    const float* __restrict__ S, const float* __restrict__ rmax, const float* __restrict__ rsumi,
    const float* __restrict__ cmax, const float* __restrict__ csumi, float* __restrict__ Vr)
{
    __shared__ float row[260];
    int n = blockIdx.x, t = threadIdx.x;
    if (t < 2) { row[t] = 0.f; row[258 + t] = 0.f; }
    float cm[5], ci[5];
#pragma unroll
    for (int d = 0; d < 5; ++d) {
        int idx = t + d - 2;
        if ((unsigned)idx < 256u) { cm[d] = cmax[n*256 + idx]; ci[d] = csumi[n*256 + idx]; }
        else { cm[d] = 0.f; ci[d] = 0.f; }
    }
    float acc = 0.f;
    const float* Sp = S + ((size_t)n << 16);
    for (int j = 0; j < 256; ++j) {
        __syncthreads();
        row[2 + t] = Sp[(j << 8) + t];
        __syncthreads();
        float relax = 0.f;
#pragma unroll
        for (int d = 0; d < 5; ++d)
            relax += __expf(row[t + d] - cm[d]) * ci[d];
        float mr2l = __expf(row[2 + t] - rmax[n*256 + j]) * rsumi[n*256 + j];
        acc = fmaf(relax, mr2l, acc);
    }
    Vr[n*256 + t] = acc;
}

// ---------------------------------------------------------------------------
// K11L: x_lT = M_r2l @ xr ; out_left = x_left*(1-t) + x_lT*t, t=tanh(5 V_l)
// ---------------------------------------------------------------------------
__global__ __launch_bounds__(256) void k_outleft(
    const float* __restrict__ S, const float* __restrict__ rmax, const float* __restrict__ rsumi,
    const float* __restrict__ Vl, const float* __restrict__ x_left, const float* __restrict__ x_right,
    float* __restrict__ out)
{
    __shared__ float Ms[64][68];   // [j'][i']
    __shared__ float Xs[64][69];   // [cc][j']
    int n = blockIdx.x; int b = n >> 7; int h = n & 127;
    int i0 = blockIdx.y*64;
    int t = threadIdx.x;
    int cg = t & 15, ig = t >> 4;
    int cc0 = cg*4, ii0 = ig*4;
    float acc[4][4] = {};
    for (int chunk = 0; chunk < 4; ++chunk) {
        int jc = chunk*64;
        __syncthreads();
        for (int idx = t; idx < 4096; idx += 256) {
            int jj = idx & 63, ii = idx >> 6;
            float mval = __expf(S[((size_t)n << 16) + (size_t)(i0 + ii)*256 + jc + jj]
                                - rmax[n*256 + i0 + ii]) * rsumi[n*256 + i0 + ii];
            Ms[jj][ii] = mval;
        }
        for (int idx = t; idx < 4096; idx += 256) {
            int jj = idx & 63, cc = idx >> 6;
            Xs[cc][jj] = x_right[(((b*64 + cc)*128 + h) << 8) + jc + jj];
        }
        __syncthreads();
        for (int j = 0; j < 64; ++j) {
            float m4[4]; *(float4*)m4 = *(const float4*)&Ms[j][ii0];
            float xv[4];
#pragma unroll
            for (int q = 0; q < 4; ++q) xv[q] = Xs[cc0 + q][j];
#pragma unroll
            for (int a = 0; a < 4; ++a)
#pragma unroll
                for (int q = 0; q < 4; ++q)
                    acc[a][q] = fmaf(m4[a], xv[q], acc[a][q]);
        }
    }
    float vl4[4]; *(float4*)vl4 = *(const float4*)&Vl[n*256 + i0 + ii0];
    float tv[4];
#pragma unroll
    for (int a = 0; a < 4; ++a) tv[a] = tanhf(5.f*vl4[a]);
#pragma unroll
    for (int q = 0; q < 4; ++q) {
        size_t base = (((size_t)(b*64 + cc0 + q)*128 + h) << 8) + i0 + ii0;
        float xl[4]; *(float4*)xl = *(const float4*)&x_left[base];
        float o4[4];
#pragma unroll
        for (int a = 0; a < 4; ++a)
            o4[a] = xl[a]*(1.f - tv[a]) + acc[a][q]*tv[a];
        *(float4*)&out[base] = *(float4*)o4;
    }
}

// ---------------------------------------------------------------------------
// K11R: x_rT = M_l2r @ xl ; out_right = x_right*(1-t) + x_rT*t, t=tanh(5 V_r)
// ---------------------------------------------------------------------------
__global__ __launch_bounds__(256) void k_outright(
    const float* __restrict__ S, const float* __restrict__ cmax, const float* __restrict__ csumi,
    const float* __restrict__ Vr, const float* __restrict__ x_left, const float* __restrict__ x_right,
    float* __restrict__ out)
{
    __shared__ float Ms[64][68];   // [i'][jq']
    __shared__ float Xs[64][69];   // [cc][i']
    int n = blockIdx.x; int b = n >> 7; int h = n & 127;
    int j0 = blockIdx.y*64;
    int t = threadIdx.x;
    int cg = t & 15, jg = t >> 4;
    int cc0 = cg*4, jj0 = jg*4;
    float acc[4][4] = {};
    for (int chunk = 0; chunk < 4; ++chunk) {
        int ic = chunk*64;
        __syncthreads();
        for (int idx = t; idx < 4096; idx += 256) {
            int jj = idx & 63, ii = idx >> 6;
            float mval = __expf(S[((size_t)n << 16) + (size_t)(ic + ii)*256 + j0 + jj]
                                - cmax[n*256 + j0 + jj]) * csumi[n*256 + j0 + jj];
            Ms[ii][jj] = mval;
        }
        for (int idx = t; idx < 4096; idx += 256) {
            int ii = idx & 63, cc = idx >> 6;
            Xs[cc][ii] = x_left[(((b*64 + cc)*128 + h) << 8) + ic + ii];
        }
        __syncthreads();
        for (int i = 0; i < 64; ++i) {
            float m4[4]; *(float4*)m4 = *(const float4*)&Ms[i][jj0];
            float xv[4];
#pragma unroll
            for (int q = 0; q < 4; ++q) xv[q] = Xs[cc0 + q][i];
#pragma unroll
            for (int a = 0; a < 4; ++a)
#pragma unroll
                for (int q = 0; q < 4; ++q)
                    acc[a][q] = fmaf(m4[a], xv[q], acc[a][q]);
        }
    }
    float vr4[4]; *(float4*)vr4 = *(const float4*)&Vr[n*256 + j0 + jj0];
    float tv[4];
#pragma unroll
    for (int a = 0; a < 4; ++a) tv[a] = tanhf(5.f*vr4[a]);
#pragma unroll
    for (int q = 0; q < 4; ++q) {
        size_t base = (((size_t)(b*64 + cc0 + q)*128 + h) << 8) + j0 + jj0;
        float xr[4]; *(float4*)xr = *(const float4*)&x_right[base];
        float o4[4];
#pragma unroll
        for (int a = 0; a < 4; ++a)
            o4[a] = xr[a]*(1.f - tv[a]) + acc[a][q]*tv[a];
        *(float4*)&out[base] = *(float4*)o4;
    }
}

// ---------------------------------------------------------------------------
extern "C" void kernel_launch(void* const* d_in, const int* in_sizes, int n_in,
                              void* d_out, int out_size, void* d_ws, size_t ws_size,
                              hipStream_t stream)
{
    const float* x_left  = (const float*)d_in[0];
    const float* x_right = (const float*)d_in[1];
    const float* conv1_w = (const float*)d_in[2];
    const float* conv1_b = (const float*)d_in[3];
    const float* conv2_w = (const float*)d_in[4];
    const float* conv2_b = (const float*)d_in[5];
    const float* bn_g    = (const float*)d_in[6];
    const float* bn_b    = (const float*)d_in[7];
    const float* bn_m    = (const float*)d_in[8];
    const float* bn_v    = (const float*)d_in[9];
    const float* rb_w1   = (const float*)d_in[10];
    const float* rb_b1   = (const float*)d_in[11];
    const float* rb_w2   = (const float*)d_in[12];
    const float* rb_b2   = (const float*)d_in[13];
    const float* bq_w    = (const float*)d_in[14];
    const float* bq_b    = (const float*)d_in[15];
    const float* bs_w    = (const float*)d_in[16];
    const float* bs_b    = (const float*)d_in[17];

    float* ws = (float*)d_ws;
    // bf16 intermediates live inside the (later) S region — dead before S write
    __hip_bfloat16* u  = (__hip_bfloat16*)(ws);             // 16.7M bf16 (8.4M f-slots)
    __hip_bfloat16* y1 = (__hip_bfloat16*)(ws + 8388608);   // 16.7M bf16
    __hip_bfloat16* r  = (__hip_bfloat16*)(ws + 16777216);  // 16.7M bf16
    float* S     = ws;                    // 33,554,432 f  (aliases u/y1/r)
    float* Qb    = ws + 33554432;         //  8,388,608
    float* Kb    = ws + 41943040;         //  8,388,608
    float* rmax  = ws + 50331648;         //    131,072
    float* rsumi = ws + 50462720;         //    131,072
    float* cmax  = ws + 50593792;         //    131,072
    float* csumi = ws + 50724864;         //    131,072
    float* Vl    = ws + 50855936;         //    131,072
    float* Vr    = ws + 50987008;         //    131,072

    float* out_left  = (float*)d_out;
    float* out_right = (float*)d_out + 8388608;

    // ---- left branch -> Q ----
    k_catbn<<<NN, 256, 0, stream>>>(x_left, conv1_w, conv1_b, bn_g, bn_b, bn_m, bn_v, u);
    k_conv3m<true,  false><<<dim3(NN, 4, 2), 256, 0, stream>>>(u, rb_w1, rb_b1, nullptr, y1);
    k_conv3m<false, true ><<<dim3(NN, 4, 2), 256, 0, stream>>>(y1, rb_w2, rb_b2, u, r);
    k_conv1x1g2<<<dim3(NN, 2), 256, 0, stream>>>(r, bq_w, bq_b, Qb);
    k_meansub<<<BB*CC*HH, 256, 0, stream>>>(Qb);

    // ---- right branch -> K ----
    k_catbn<<<NN, 256, 0, stream>>>(x_right, conv2_w, conv2_b, bn_g, bn_b, bn_m, bn_v, u);
    k_conv3m<true,  false><<<dim3(NN, 4, 2), 256, 0, stream>>>(u, rb_w1, rb_b1, nullptr, y1);
    k_conv3m<false, true ><<<dim3(NN, 4, 2), 256, 0, stream>>>(y1, rb_w2, rb_b2, u, r);
    k_conv1x1g2<<<dim3(NN, 2), 256, 0, stream>>>(r, bs_w, bs_b, Kb);
    k_meansub<<<BB*CC*HH, 256, 0, stream>>>(Kb);

    // ---- attention ----
    k_score<<<dim3(NN, 4, 2), 256, 0, stream>>>(Qb, Kb, S);
    k_rowstats<<<dim3(256, NN), 256, 0, stream>>>(S, rmax, rsumi);
    k_colstats<<<NN, 256, 0, stream>>>(S, cmax, csumi);
    k_vl<<<dim3(256, NN), 256, 0, stream>>>(S, rmax, rsumi, cmax, csumi, Vl);
    k_vr<<<NN, 256, 0, stream>>>(S, rmax, rsumi, cmax, csumi, Vr);
    k_outleft<<<dim3(NN, 4), 256, 0, stream>>>(S, rmax, rsumi, Vl, x_left, x_right, out_left);
    k_outright<<<dim3(NN, 4), 256, 0, stream>>>(S, cmax, csumi, Vr, x_left, x_right, out_right);
}

// Round 3
// 1147.607 us; speedup vs baseline: 3.1913x; 1.1919x over previous
//
#include <hip/hip_runtime.h>
#include <math.h>

// Problem constants
#define BB 4
#define CC 64
#define C2 128
#define HH 128
#define WW 256
#define NN (BB*HH)          // 512 row-pairs
#define EPSBN 1e-5f

typedef _Float16 f16;
typedef _Float16 half8 __attribute__((ext_vector_type(8)));
typedef float f32x4 __attribute__((ext_vector_type(4)));

// ---------------------------------------------------------------------------
// K1: fused 1x1 conv (64->64) + concat + batchnorm -> u  (channel-last f16)
// u[n][w][128].  grid: 512 = (b,h); 256 threads = w pixel.
// ---------------------------------------------------------------------------
__global__ __launch_bounds__(256) void k_catbn(
    const float* __restrict__ x, const float* __restrict__ cw, const float* __restrict__ cb,
    const float* __restrict__ g, const float* __restrict__ bb_, const float* __restrict__ m,
    const float* __restrict__ v, f16* __restrict__ u)
{
    __shared__ float Wl[64][68];
    __shared__ float sS[64], sT[64], sS2[64], sT2[64];
    int n = blockIdx.x; int b = n >> 7; int h = n & 127; int t = threadIdx.x;
    for (int idx = t; idx < 4096; idx += 256) Wl[idx >> 6][idx & 63] = cw[idx];
    if (t < 64) {
        float inv = rsqrtf(v[t] + EPSBN); float s = g[t] * inv;
        sS[t] = s; sT[t] = bb_[t] + s * (cb[t] - m[t]);
        float inv2 = rsqrtf(v[t + 64] + EPSBN); float s2 = g[t + 64] * inv2;
        sS2[t] = s2; sT2[t] = bb_[t + 64] - s2 * m[t + 64];
    }
    float xv[64];
#pragma unroll
    for (int i = 0; i < 64; ++i)
        xv[i] = x[(((b*64 + i)*128 + h) << 8) + t];
    __syncthreads();
    f16* up = u + ((size_t)(n*256 + t)) * 128;
    for (int o8 = 0; o8 < 8; ++o8) {
        union { f16 h[8]; uint4 v4; } pk;
#pragma unroll
        for (int oo = 0; oo < 8; ++oo) {
            int o = o8*8 + oo;
            float acc = 0.f;
#pragma unroll
            for (int i4 = 0; i4 < 16; ++i4) {
                float4 w4 = *(const float4*)&Wl[o][i4*4];
                acc = fmaf(w4.x, xv[i4*4+0], acc);
                acc = fmaf(w4.y, xv[i4*4+1], acc);
                acc = fmaf(w4.z, xv[i4*4+2], acc);
                acc = fmaf(w4.w, xv[i4*4+3], acc);
            }
            pk.h[oo] = (f16)(sS[o]*acc + sT[o]);
        }
        *(uint4*)(up + o8*8) = pk.v4;
    }
    for (int o8 = 0; o8 < 8; ++o8) {
        union { f16 h[8]; uint4 v4; } pk;
#pragma unroll
        for (int oo = 0; oo < 8; ++oo) {
            int i = o8*8 + oo;
            pk.h[oo] = (f16)(sS2[i]*xv[i] + sT2[i]);
        }
        *(uint4*)(up + 64 + o8*8) = pk.v4;
    }
}

// ---------------------------------------------------------------------------
// K2/K3: grouped 3x3 conv via implicit-GEMM f16 MFMA 16x16x32.
// In/out channel-last f16 [n][w][128].  K reordered: k=(ky*3+kx)*32+ic.
// grid (512 bh, 4 group, 2 wtile); 256 thr = 4 waves; wave: 32px x 32oc.
// ---------------------------------------------------------------------------
template<bool LEAKY, bool RES>
__global__ __launch_bounds__(256) void k_conv3m(
    const f16* __restrict__ in, const float* __restrict__ wgt,
    const float* __restrict__ bias, const f16* __restrict__ res,
    f16* __restrict__ out)
{
    __shared__ f16 Wl[32*296];    // [mo][k] stride 296
    __shared__ f16 Xl[3*130*40];  // [row][px][ic] px-stride 40
    int n = blockIdx.x; int b = n >> 7; int h = n & 127;
    int g = blockIdx.y; int w0 = blockIdx.z * 128;
    int t = threadIdx.x;
    for (int p = t; p < 4608; p += 256) {
        int kidx = p * 2;
        int mo = kidx / 288; int kr = kidx - mo*288;
        int ic = kr & 31; int ks = kr >> 5;
        int gb = ((g*32 + mo)*32 + ic)*9 + ks;
        union { f16 h[2]; unsigned int u; } pr;
        pr.h[0] = (f16)wgt[gb];
        pr.h[1] = (f16)wgt[gb + 9];   // ic+1, same (ky,kx)
        *(unsigned int*)&Wl[mo*296 + kr] = pr.u;
    }
    for (int idx = t; idx < 1560; idx += 256) {
        int r = idx / 520; int rem = idx - r*520; int p = rem >> 2; int q = rem & 3;
        int hr = h + r - 1; int wg = w0 + p - 1;
        uint4 val = make_uint4(0,0,0,0);
        if (p < 130 && (unsigned)wg < 256u && (unsigned)hr < 128u)
            val = *(const uint4*)(in + ((size_t)((b*128 + hr)*256 + wg))*128 + g*32 + q*8);
        if (p < 130)
            *(uint4*)&Xl[(r*130 + p)*40 + q*8] = val;
    }
    __syncthreads();
    int lane = t & 63, wv = t >> 6;
    int m16 = lane & 15, quad = lane >> 4;
    f32x4 acc[2][2] = {};
#pragma unroll
    for (int ks = 0; ks < 9; ++ks) {
        int ky = ks / 3, kx = ks - ky*3;
        half8 af0 = *(const half8*)&Wl[m16*296 + ks*32 + quad*8];
        half8 af1 = *(const half8*)&Wl[(16 + m16)*296 + ks*32 + quad*8];
        int px0 = wv*32 + m16;
        half8 bf0 = *(const half8*)&Xl[(ky*130 + px0 + kx)*40 + quad*8];
        half8 bf1 = *(const half8*)&Xl[(ky*130 + px0 + 16 + kx)*40 + quad*8];
        acc[0][0] = __builtin_amdgcn_mfma_f32_16x16x32_f16(af0, bf0, acc[0][0], 0, 0, 0);
        acc[0][1] = __builtin_amdgcn_mfma_f32_16x16x32_f16(af0, bf1, acc[0][1], 0, 0, 0);
        acc[1][0] = __builtin_amdgcn_mfma_f32_16x16x32_f16(af1, bf0, acc[1][0], 0, 0, 0);
        acc[1][1] = __builtin_amdgcn_mfma_f32_16x16x32_f16(af1, bf1, acc[1][1], 0, 0, 0);
    }
    float bo[2][4];
#pragma unroll
    for (int mt = 0; mt < 2; ++mt)
#pragma unroll
        for (int r = 0; r < 4; ++r)
            bo[mt][r] = bias[g*32 + mt*16 + quad*4 + r];
#pragma unroll
    for (int mt = 0; mt < 2; ++mt)
#pragma unroll
        for (int nt = 0; nt < 2; ++nt) {
            int px = w0 + wv*32 + nt*16 + m16;
            int oc = g*32 + mt*16 + quad*4;
            size_t off = ((size_t)((b*128 + h)*256 + px))*128 + oc;
            float rv4[4] = {0.f, 0.f, 0.f, 0.f};
            if (RES) {
                union { f16 h[4]; uint2 v2; } rr;
                rr.v2 = *(const uint2*)(res + off);
#pragma unroll
                for (int r = 0; r < 4; ++r) rv4[r] = (float)rr.h[r];
            }
            union { f16 h[4]; uint2 v2; } ov;
#pragma unroll
            for (int r = 0; r < 4; ++r) {
                float y = acc[mt][nt][r] + bo[mt][r];
                if (LEAKY) y = y > 0.f ? y : 0.1f*y;
                if (RES) y += rv4[r];
                ov.h[r] = (f16)y;
            }
            *(uint2*)(out + off) = ov.v2;
        }
}

// ---------------------------------------------------------------------------
// K4: grouped 1x1 conv (128->64, groups=2) + row-mean subtraction fused.
// Bias cancels under mean-sub (Q - mean(Q)).  Out: f16 [n][i][64] MFMA-ready.
// grid (512 bh, 2 group); 256 threads = w pixel.
// ---------------------------------------------------------------------------
__global__ __launch_bounds__(256) void k_conv1x1m(
    const f16* __restrict__ in, const float* __restrict__ wgt,
    f16* __restrict__ outq)
{
    __shared__ float Wl[32][68];
    __shared__ float Ab[32][260];
    __shared__ float meanS[32];
    int n = blockIdx.x; int g = blockIdx.y; int t = threadIdx.x;
    int lane = t & 63, wv = t >> 6;
    for (int idx = t; idx < 2048; idx += 256) Wl[idx >> 6][idx & 63] = wgt[g*2048 + idx];
    float rv[64];
    const f16* rp = in + ((size_t)n*256 + t)*128 + g*64;
#pragma unroll
    for (int i8 = 0; i8 < 8; ++i8) {
        union { uint4 v4; f16 h[8]; } ld;
        ld.v4 = *(const uint4*)(rp + i8*8);
#pragma unroll
        for (int j = 0; j < 8; ++j) rv[i8*8 + j] = (float)ld.h[j];
    }
    __syncthreads();
    float acc[32];
#pragma unroll
    for (int ol = 0; ol < 32; ++ol) {
        float a = 0.f;
#pragma unroll
        for (int i4 = 0; i4 < 16; ++i4) {
            float4 w4 = *(const float4*)&Wl[ol][i4*4];
            a = fmaf(w4.x, rv[i4*4+0], a);
            a = fmaf(w4.y, rv[i4*4+1], a);
            a = fmaf(w4.z, rv[i4*4+2], a);
            a = fmaf(w4.w, rv[i4*4+3], a);
        }
        acc[ol] = a;
        Ab[ol][t] = a;
    }
    __syncthreads();
#pragma unroll
    for (int k = 0; k < 8; ++k) {
        int o = wv*8 + k;
        float s = Ab[o][lane] + Ab[o][lane+64] + Ab[o][lane+128] + Ab[o][lane+192];
#pragma unroll
        for (int off = 32; off; off >>= 1) s += __shfl_xor(s, off);
        if (lane == 0) meanS[o] = s * (1.0f/256.0f);
    }
    __syncthreads();
    f16* qp = outq + ((size_t)n*256 + t)*64 + g*32;
#pragma unroll
    for (int o8 = 0; o8 < 4; ++o8) {
        union { uint4 v4; f16 h[8]; } pk;
#pragma unroll
        for (int e = 0; e < 8; ++e)
            pk.h[e] = (f16)(acc[o8*8+e] - meanS[o8*8+e]);
        *(uint4*)(qp + o8*8) = pk.v4;
    }
}

// ---------------------------------------------------------------------------
// K5: score S = Q K^T per n via MFMA f16.  Q,K: [n][256][64] f16.
// Writes S[n][i][j] and ST[n][j][i] (both f16).  grid 512; 256 thr.
// ---------------------------------------------------------------------------
__global__ __launch_bounds__(256) void k_score(
    const f16* __restrict__ Q, const f16* __restrict__ K,
    f16* __restrict__ S, f16* __restrict__ ST)
{
    __shared__ f16 Qs[256][72];
    __shared__ f16 Ks[64][72];
    int n = blockIdx.x; int t = threadIdx.x;
    const f16* qg = Q + (size_t)n*16384 + (size_t)t*64;
#pragma unroll
    for (int k = 0; k < 8; ++k)
        *(uint4*)&Qs[t][k*8] = *(const uint4*)(qg + k*8);
    int lane = t & 63, wv = t >> 6;
    int m16 = lane & 15, quad = lane >> 4;
    int m0 = wv*64;
    half8 af[4][2];
    bool afl = false;
    f16* Sn = S + (size_t)n*65536;
    f16* STn = ST + (size_t)n*65536;
    for (int jc = 0; jc < 256; jc += 64) {
        __syncthreads();   // Qs ready (first iter) / Ks consumers done (later)
        {
            int jj = t >> 2, seg = (t & 3) * 16;
            const f16* kg = K + (size_t)n*16384 + (size_t)(jc + jj)*64 + seg;
            *(uint4*)&Ks[jj][seg]     = *(const uint4*)(kg);
            *(uint4*)&Ks[jj][seg + 8] = *(const uint4*)(kg + 8);
        }
        __syncthreads();
        if (!afl) {
            afl = true;
#pragma unroll
            for (int mt = 0; mt < 4; ++mt)
#pragma unroll
                for (int kk = 0; kk < 2; ++kk)
                    af[mt][kk] = *(const half8*)&Qs[m0 + mt*16 + m16][kk*32 + quad*8];
        }
        half8 bf[4][2];
#pragma unroll
        for (int nt = 0; nt < 4; ++nt)
#pragma unroll
            for (int kk = 0; kk < 2; ++kk)
                bf[nt][kk] = *(const half8*)&Ks[nt*16 + m16][kk*32 + quad*8];
        f32x4 acc[4][4] = {};
#pragma unroll
        for (int mt = 0; mt < 4; ++mt)
#pragma unroll
            for (int nt = 0; nt < 4; ++nt) {
                acc[mt][nt] = __builtin_amdgcn_mfma_f32_16x16x32_f16(af[mt][0], bf[nt][0], acc[mt][nt], 0, 0, 0);
                acc[mt][nt] = __builtin_amdgcn_mfma_f32_16x16x32_f16(af[mt][1], bf[nt][1], acc[mt][nt], 0, 0, 0);
            }
#pragma unroll
        for (int mt = 0; mt < 4; ++mt)
#pragma unroll
            for (int nt = 0; nt < 4; ++nt) {
                int i = m0 + mt*16 + quad*4;
                int j = jc + nt*16 + m16;
#pragma unroll
                for (int r = 0; r < 4; ++r) {
                    f16 vv = (f16)acc[mt][nt][r];
                    Sn[(size_t)(i + r)*256 + j] = vv;
                    STn[(size_t)j*256 + (i + r)] = vv;
                }
            }
    }
}

// ---------------------------------------------------------------------------
// K6: softmax stats.  grid (512 n, 2 half): rows r0..r0+127.
// Row stats exact (full row in block); col stats as online partials per half.
// ---------------------------------------------------------------------------
__global__ __launch_bounds__(256) void k_stats(
    const f16* __restrict__ S, float* __restrict__ rmax, float* __restrict__ rsumi,
    float* __restrict__ cpm, float* __restrict__ cps)
{
    __shared__ float red[4], red2[4];
    int n = blockIdx.x, h2 = blockIdx.y, t = threadIdx.x;
    int r0 = h2*128;
    int lane = t & 63, wid = t >> 6;
    const f16* Sp = S + (size_t)n*65536 + (size_t)r0*256 + t;
    float cm = -1e30f, cs = 0.f;
    float cur = (float)Sp[0];
    for (int s = 0; s < 128; ++s) {
        float nxt = (s < 127) ? (float)Sp[(size_t)(s+1)*256] : 0.f;
        float mx = cur;
#pragma unroll
        for (int off = 32; off; off >>= 1) mx = fmaxf(mx, __shfl_xor(mx, off));
        if (lane == 0) red[wid] = mx;
        __syncthreads();
        mx = fmaxf(fmaxf(red[0], red[1]), fmaxf(red[2], red[3]));
        float e = __expf(cur - mx);
#pragma unroll
        for (int off = 32; off; off >>= 1) e += __shfl_xor(e, off);
        if (lane == 0) red2[wid] = e;
        __syncthreads();
        if (t == 0) {
            float sum = red2[0] + red2[1] + red2[2] + red2[3];
            rmax[n*256 + r0 + s] = mx;
            rsumi[n*256 + r0 + s] = 1.0f / sum;
        }
        float nm = fmaxf(cm, cur);
        cs = cs*__expf(cm - nm) + __expf(cur - nm);
        cm = nm;
        cur = nxt;
    }
    cpm[(n*2 + h2)*256 + t] = cm;
    cps[(n*2 + h2)*256 + t] = cs;
}

// ---------------------------------------------------------------------------
// K7: fused V_l + V_r in one S stream.  grid (512 n, 2 half).
// Streams rows r0-2..r0+129 with 5-row register window + LDS halo row.
// Also writes merged cmax/csumi (h2==0).
// ---------------------------------------------------------------------------
__global__ __launch_bounds__(256) void k_v(
    const f16* __restrict__ S, const float* __restrict__ rmax, const float* __restrict__ rsumi,
    const float* __restrict__ cpm, const float* __restrict__ cps,
    float* __restrict__ cmax, float* __restrict__ csumi,
    float* __restrict__ Vl, float* __restrict__ Vr0, float* __restrict__ Vr1)
{
    __shared__ float cmS[256], ciS[256];
    __shared__ float rmS[132], riS[132];
    __shared__ float rowbuf[260];
    __shared__ float red[4];
    int n = blockIdx.x, h2 = blockIdx.y, t = threadIdx.x;
    int r0 = h2*128;
    int lane = t & 63, wid = t >> 6;
    float m0 = cpm[(n*2+0)*256+t], s0 = cps[(n*2+0)*256+t];
    float m1 = cpm[(n*2+1)*256+t], s1 = cps[(n*2+1)*256+t];
    float cm = fmaxf(m0, m1);
    float cs = s0*__expf(m0-cm) + s1*__expf(m1-cm);
    float ci = 1.0f/cs;
    cmS[t] = cm; ciS[t] = ci;
    if (h2 == 0) { cmax[n*256+t] = cm; csumi[n*256+t] = ci; }
    if (t < 132) {
        int rr = r0 - 2 + t;
        if ((unsigned)rr < 256u) { rmS[t] = rmax[n*256+rr]; riS[t] = rsumi[n*256+rr]; }
        else { rmS[t] = 0.f; riS[t] = 0.f; }
    }
    if (t < 2) { rowbuf[t] = 0.f; rowbuf[258+t] = 0.f; }
    __syncthreads();
    float cmr[5], cir[5];
#pragma unroll
    for (int d = 0; d < 5; ++d) {
        int idx = t + d - 2;
        if ((unsigned)idx < 256u) { cmr[d] = cmS[idx]; cir[d] = ciS[idx]; }
        else { cmr[d] = 0.f; cir[d] = 0.f; }
    }
    const f16* Sp = S + (size_t)n*65536 + t;
    float w0=0.f, w1=0.f, w2=0.f, w3=0.f, w4=0.f;
    float vr = 0.f;
    int rr0 = r0 - 2;
    float pf = ((unsigned)rr0 < 256u) ? (float)Sp[(size_t)rr0*256] : 0.f;
    for (int s = 0; s < 132; ++s) {
        float cur = pf;
        int rn = rr0 + s + 1;
        pf = ((unsigned)rn < 256u) ? (float)Sp[(size_t)rn*256] : 0.f;
        w0=w1; w1=w2; w2=w3; w3=w4; w4=cur;
        rowbuf[2 + t] = cur;
        __syncthreads();
        if (s >= 2 && s <= 129) {
            float pr = __expf(cur - rmS[s]) * riS[s];
            float relaxc = 0.f;
#pragma unroll
            for (int d = 0; d < 5; ++d)
                relaxc += __expf(rowbuf[t + d] - cmr[d]) * cir[d];
            vr = fmaf(relaxc, pr, vr);
        }
        if (s >= 4) {
            float relaxr = __expf(w0 - rmS[s-4])*riS[s-4]
                         + __expf(w1 - rmS[s-3])*riS[s-3]
                         + __expf(w2 - rmS[s-2])*riS[s-2]
                         + __expf(w3 - rmS[s-1])*riS[s-1]
                         + __expf(w4 - rmS[s  ])*riS[s  ];
            float pl = relaxr * __expf(w2 - cmS[t]) * ciS[t];
#pragma unroll
            for (int off = 32; off; off >>= 1) pl += __shfl_xor(pl, off);
            if (lane == 0) red[wid] = pl;
        }
        __syncthreads();
        if (s >= 4 && t == 0)
            Vl[n*256 + r0 + s - 4] = red[0] + red[1] + red[2] + red[3];
    }
    float* Vrp = h2 ? Vr1 : Vr0;
    Vrp[n*256 + t] = vr;
}

// ---------------------------------------------------------------------------
// K8: out = xP*(1-t) + (P @ xB)*t,  t = tanh(5 V).   MFMA f16.
// P rows from P16 (S for left / ST for right) with exp(v - sm[row])*si[row].
// grid 512 n; 256 thr; LDS 46KB.
// ---------------------------------------------------------------------------
__global__ __launch_bounds__(256) void k_out(
    const f16* __restrict__ P16, const float* __restrict__ sm, const float* __restrict__ si,
    const float* __restrict__ V1, const float* __restrict__ V2,
    const float* __restrict__ xB, const float* __restrict__ xP,
    float* __restrict__ outp)
{
    __shared__ f16 Pl[256][72];
    __shared__ f16 Xl[64][72];
    int n = blockIdx.x; int b = n >> 7; int h = n & 127;
    int t = threadIdx.x;
    int lane = t & 63, wv = t >> 6;
    int m16 = lane & 15, quad = lane >> 4;
    float rm = sm[n*256 + t], ri = si[n*256 + t];
    f32x4 acc[4][4] = {};
    for (int kc = 0; kc < 256; kc += 64) {
        const f16* pg = P16 + (size_t)n*65536 + (size_t)t*256 + kc;
#pragma unroll
        for (int k8 = 0; k8 < 8; ++k8) {
            union { uint4 v4; f16 h[8]; } ldu, stu;
            ldu.v4 = *(const uint4*)(pg + k8*8);
#pragma unroll
            for (int e = 0; e < 8; ++e)
                stu.h[e] = (f16)(__expf((float)ldu.h[e] - rm) * ri);
            *(uint4*)&Pl[t][k8*8] = stu.v4;
        }
        {
            int c = t >> 2, j0 = (t & 3) * 16;
            const float* xg = xB + (((size_t)(b*64 + c)*128 + h) << 8) + kc + j0;
            union { uint4 v4; f16 h[8]; } xu0, xu1;
#pragma unroll
            for (int e = 0; e < 8; ++e) xu0.h[e] = (f16)xg[e];
#pragma unroll
            for (int e = 0; e < 8; ++e) xu1.h[e] = (f16)xg[8 + e];
            *(uint4*)&Xl[c][j0]     = xu0.v4;
            *(uint4*)&Xl[c][j0 + 8] = xu1.v4;
        }
        __syncthreads();
        int mbase = wv*64;
        half8 a0[4][2], b0[4][2];
#pragma unroll
        for (int mt = 0; mt < 4; ++mt)
#pragma unroll
            for (int kk = 0; kk < 2; ++kk)
                a0[mt][kk] = *(const half8*)&Pl[mbase + mt*16 + m16][kk*32 + quad*8];
#pragma unroll
        for (int nt = 0; nt < 4; ++nt)
#pragma unroll
            for (int kk = 0; kk < 2; ++kk)
                b0[nt][kk] = *(const half8*)&Xl[nt*16 + m16][kk*32 + quad*8];
#pragma unroll
        for (int mt = 0; mt < 4; ++mt)
#pragma unroll
            for (int nt = 0; nt < 4; ++nt) {
                acc[mt][nt] = __builtin_amdgcn_mfma_f32_16x16x32_f16(a0[mt][0], b0[nt][0], acc[mt][nt], 0, 0, 0);
                acc[mt][nt] = __builtin_amdgcn_mfma_f32_16x16x32_f16(a0[mt][1], b0[nt][1], acc[mt][nt], 0, 0, 0);
            }
        __syncthreads();
    }
#pragma unroll
    for (int mt = 0; mt < 4; ++mt) {
        int i0 = wv*64 + mt*16 + quad*4;
        float v4[4];
        *(float4*)v4 = *(const float4*)&V1[n*256 + i0];
        if (V2) {
            float u4[4]; *(float4*)u4 = *(const float4*)&V2[n*256 + i0];
#pragma unroll
            for (int r = 0; r < 4; ++r) v4[r] += u4[r];
        }
        float tv[4];
#pragma unroll
        for (int r = 0; r < 4; ++r) tv[r] = tanhf(5.f*v4[r]);
#pragma unroll
        for (int nt = 0; nt < 4; ++nt) {
            int c = nt*16 + m16;
            size_t base = (((size_t)(b*64 + c)*128 + h) << 8) + i0;
            float xp4[4]; *(float4*)xp4 = *(const float4*)&xP[base];
            float o4[4];
#pragma unroll
            for (int r = 0; r < 4; ++r)
                o4[r] = xp4[r]*(1.f - tv[r]) + acc[mt][nt][r]*tv[r];
            *(float4*)&outp[base] = *(float4*)o4;
        }
    }
}

// ---------------------------------------------------------------------------
extern "C" void kernel_launch(void* const* d_in, const int* in_sizes, int n_in,
                              void* d_out, int out_size, void* d_ws, size_t ws_size,
                              hipStream_t stream)
{
    const float* x_left  = (const float*)d_in[0];
    const float* x_right = (const float*)d_in[1];
    const float* conv1_w = (const float*)d_in[2];
    const float* conv1_b = (const float*)d_in[3];
    const float* conv2_w = (const float*)d_in[4];
    const float* conv2_b = (const float*)d_in[5];
    const float* bn_g    = (const float*)d_in[6];
    const float* bn_b    = (const float*)d_in[7];
    const float* bn_m    = (const float*)d_in[8];
    const float* bn_v    = (const float*)d_in[9];
    const float* rb_w1   = (const float*)d_in[10];
    const float* rb_b1   = (const float*)d_in[11];
    const float* rb_w2   = (const float*)d_in[12];
    const float* rb_b2   = (const float*)d_in[13];
    const float* bq_w    = (const float*)d_in[14];
    const float* bs_w    = (const float*)d_in[16];

    f16* W16 = (f16*)d_ws;
    // f16 regions (element offsets). u/y1 alias S; r aliases ST (all dead by then).
    f16* u  = W16;                       // 16,777,216 els
    f16* y1 = W16 + 16777216;            // 16,777,216
    f16* r  = W16 + 33554432;            // 16,777,216
    f16* S  = W16;                       // 33,554,432 (aliases u+y1)
    f16* ST = W16 + 33554432;            // 33,554,432 (aliases r + fresh)
    f16* Qh = W16 + 67108864;            //  8,388,608
    f16* Kh = W16 + 75497472;            //  8,388,608
    float* F32  = (float*)(W16 + 83886080);
    float* rmax  = F32;                  // 131,072
    float* rsumi = F32 + 131072;
    float* cpm   = F32 + 262144;         // 262,144
    float* cps   = F32 + 524288;         // 262,144
    float* cmax  = F32 + 786432;         // 131,072
    float* csumi = F32 + 917504;         // 131,072
    float* Vl    = F32 + 1048576;        // 131,072
    float* Vr0   = F32 + 1179648;        // 131,072
    float* Vr1   = F32 + 1310720;        // 131,072

    float* out_left  = (float*)d_out;
    float* out_right = (float*)d_out + 8388608;

    // ---- left branch -> Q ----
    k_catbn<<<NN, 256, 0, stream>>>(x_left, conv1_w, conv1_b, bn_g, bn_b, bn_m, bn_v, u);
    k_conv3m<true,  false><<<dim3(NN, 4, 2), 256, 0, stream>>>(u, rb_w1, rb_b1, nullptr, y1);
    k_conv3m<false, true ><<<dim3(NN, 4, 2), 256, 0, stream>>>(y1, rb_w2, rb_b2, u, r);
    k_conv1x1m<<<dim3(NN, 2), 256, 0, stream>>>(r, bq_w, Qh);

    // ---- right branch -> K ----
    k_catbn<<<NN, 256, 0, stream>>>(x_right, conv2_w, conv2_b, bn_g, bn_b, bn_m, bn_v, u);
    k_conv3m<true,  false><<<dim3(NN, 4, 2), 256, 0, stream>>>(u, rb_w1, rb_b1, nullptr, y1);
    k_conv3m<false, true ><<<dim3(NN, 4, 2), 256, 0, stream>>>(y1, rb_w2, rb_b2, u, r);
    k_conv1x1m<<<dim3(NN, 2), 256, 0, stream>>>(r, bs_w, Kh);

    // ---- attention ----
    k_score<<<NN, 256, 0, stream>>>(Qh, Kh, S, ST);
    k_stats<<<dim3(NN, 2), 256, 0, stream>>>(S, rmax, rsumi, cpm, cps);
    k_v<<<dim3(NN, 2), 256, 0, stream>>>(S, rmax, rsumi, cpm, cps, cmax, csumi, Vl, Vr0, Vr1);
    k_out<<<NN, 256, 0, stream>>>(S,  rmax, rsumi, Vl,  nullptr, x_right, x_left,  out_left);
    k_out<<<NN, 256, 0, stream>>>(ST, cmax, csumi, Vr0, Vr1,     x_left,  x_right, out_right);
}

// Round 4
// 948.775 us; speedup vs baseline: 3.8601x; 1.2096x over previous
//
#include <hip/hip_runtime.h>
#include <math.h>

// Problem constants
#define BB 4
#define CC 64
#define C2 128
#define HH 128
#define WW 256
#define NN (BB*HH)          // 512 row-pairs
#define EPSBN 1e-5f

typedef _Float16 f16;
typedef _Float16 half8 __attribute__((ext_vector_type(8)));
typedef float f32x4 __attribute__((ext_vector_type(4)));

// ---------------------------------------------------------------------------
// K1: fused 1x1 conv (64->64) + concat + batchnorm -> u (channel-last f16)
// via MFMA 16x16x32 f16.  u[n][px][128].  grid 512 = (b,h); 256 thr = 4 waves.
// A = W [oc][ic] (m=oc), B = x^T [px][ic] (n=px), both k=ic contiguous in LDS.
// ---------------------------------------------------------------------------
__global__ __launch_bounds__(256) void k_catbn_m(
    const float* __restrict__ x, const float* __restrict__ cw, const float* __restrict__ cb,
    const float* __restrict__ g, const float* __restrict__ bb_, const float* __restrict__ m,
    const float* __restrict__ v, f16* __restrict__ u)
{
    __shared__ f16 Xl[256][72];   // [px][ic], stride 72 f16 = 144 B (b128-aligned)
    __shared__ f16 Wl[64][72];    // [oc][ic]
    __shared__ float sS[64], sT[64], sS2[64], sT2[64];
    int n = blockIdx.x; int b = n >> 7; int h = n & 127; int t = threadIdx.x;
    // stage weights: pack 2 f16 per u32 write (conflict-free)
    for (int p = t; p < 2048; p += 256) {
        int idx = p * 2; int o = idx >> 6, i = idx & 63;
        union { f16 h[2]; unsigned int u1; } pr;
        pr.h[0] = (f16)cw[idx]; pr.h[1] = (f16)cw[idx + 1];
        *(unsigned int*)&Wl[o][i] = pr.u1;
    }
    if (t < 64) {
        float inv = rsqrtf(v[t] + EPSBN); float s = g[t] * inv;
        sS[t] = s; sT[t] = bb_[t] + s * (cb[t] - m[t]);
        float inv2 = rsqrtf(v[t + 64] + EPSBN); float s2 = g[t + 64] * inv2;
        sS2[t] = s2; sT2[t] = bb_[t + 64] - s2 * m[t + 64];
    }
    __syncthreads();
    // load x (coalesced per-channel rows), emit concat-half, stage transpose
    f16* up = u + ((size_t)(n*256 + t)) * 128;
    for (int c8 = 0; c8 < 8; ++c8) {
        float xv8[8];
#pragma unroll
        for (int j = 0; j < 8; ++j)
            xv8[j] = x[(((b*64 + c8*8 + j)*128 + h) << 8) + t];
        union { f16 h[8]; uint4 v4; } pk;
#pragma unroll
        for (int j = 0; j < 8; ++j) {
            int c = c8*8 + j;
            pk.h[j] = (f16)(sS2[c]*xv8[j] + sT2[c]);
        }
        *(uint4*)(up + 64 + c8*8) = pk.v4;     // u[px][64+c]
#pragma unroll
        for (int j2 = 0; j2 < 4; ++j2) {        // transposed LDS stage
            union { f16 h[2]; unsigned int u1; } q;
            q.h[0] = (f16)xv8[j2*2]; q.h[1] = (f16)xv8[j2*2 + 1];
            *(unsigned int*)&Xl[t][c8*8 + j2*2] = q.u1;
        }
    }
    __syncthreads();
    // MFMA: wave wv covers px range [wv*64, wv*64+64)
    int lane = t & 63, wv = t >> 6;
    int m16 = lane & 15, quad = lane >> 4;
    half8 af[4][2], bf[4][2];
#pragma unroll
    for (int mt = 0; mt < 4; ++mt)
#pragma unroll
        for (int kk = 0; kk < 2; ++kk)
            af[mt][kk] = *(const half8*)&Wl[mt*16 + m16][kk*32 + quad*8];
#pragma unroll
    for (int nt = 0; nt < 4; ++nt)
#pragma unroll
        for (int kk = 0; kk < 2; ++kk)
            bf[nt][kk] = *(const half8*)&Xl[wv*64 + nt*16 + m16][kk*32 + quad*8];
    f32x4 acc[4][4] = {};
#pragma unroll
    for (int mt = 0; mt < 4; ++mt)
#pragma unroll
        for (int nt = 0; nt < 4; ++nt) {
            acc[mt][nt] = __builtin_amdgcn_mfma_f32_16x16x32_f16(af[mt][0], bf[nt][0], acc[mt][nt], 0, 0, 0);
            acc[mt][nt] = __builtin_amdgcn_mfma_f32_16x16x32_f16(af[mt][1], bf[nt][1], acc[mt][nt], 0, 0, 0);
        }
    // epilogue: u[px][oc] = sS[oc]*acc + sT[oc]; lane holds 4 consecutive oc
#pragma unroll
    for (int mt = 0; mt < 4; ++mt) {
        int ocb = mt*16 + quad*4;
        float s4[4], t4[4];
        *(float4*)s4 = *(const float4*)&sS[ocb];
        *(float4*)t4 = *(const float4*)&sT[ocb];
#pragma unroll
        for (int nt = 0; nt < 4; ++nt) {
            int px = wv*64 + nt*16 + m16;
            union { f16 h[4]; uint2 u2; } ov;
#pragma unroll
            for (int r = 0; r < 4; ++r)
                ov.h[r] = (f16)(s4[r]*acc[mt][nt][r] + t4[r]);
            *(uint2*)(u + ((size_t)(n*256 + px))*128 + ocb) = ov.u2;
        }
    }
}

// ---------------------------------------------------------------------------
// K2/K3: grouped 3x3 conv via implicit-GEMM f16 MFMA 16x16x32.
// In/out channel-last f16 [n][w][128].  K reordered: k=(ky*3+kx)*32+ic.
// grid (512 bh, 4 group, 2 wtile); 256 thr = 4 waves; wave: 32px x 32oc.
// ---------------------------------------------------------------------------
template<bool LEAKY, bool RES>
__global__ __launch_bounds__(256) void k_conv3m(
    const f16* __restrict__ in, const float* __restrict__ wgt,
    const float* __restrict__ bias, const f16* __restrict__ res,
    f16* __restrict__ out)
{
    __shared__ f16 Wl[32*296];    // [mo][k] stride 296
    __shared__ f16 Xl[3*130*40];  // [row][px][ic] px-stride 40
    int n = blockIdx.x; int b = n >> 7; int h = n & 127;
    int g = blockIdx.y; int w0 = blockIdx.z * 128;
    int t = threadIdx.x;
    for (int p = t; p < 4608; p += 256) {
        int kidx = p * 2;
        int mo = kidx / 288; int kr = kidx - mo*288;
        int ic = kr & 31; int ks = kr >> 5;
        int gb = ((g*32 + mo)*32 + ic)*9 + ks;
        union { f16 h[2]; unsigned int u; } pr;
        pr.h[0] = (f16)wgt[gb];
        pr.h[1] = (f16)wgt[gb + 9];   // ic+1, same (ky,kx)
        *(unsigned int*)&Wl[mo*296 + kr] = pr.u;
    }
    for (int idx = t; idx < 1560; idx += 256) {
        int r = idx / 520; int rem = idx - r*520; int p = rem >> 2; int q = rem & 3;
        int hr = h + r - 1; int wg = w0 + p - 1;
        uint4 val = make_uint4(0,0,0,0);
        if (p < 130 && (unsigned)wg < 256u && (unsigned)hr < 128u)
            val = *(const uint4*)(in + ((size_t)((b*128 + hr)*256 + wg))*128 + g*32 + q*8);
        if (p < 130)
            *(uint4*)&Xl[(r*130 + p)*40 + q*8] = val;
    }
    __syncthreads();
    int lane = t & 63, wv = t >> 6;
    int m16 = lane & 15, quad = lane >> 4;
    f32x4 acc[2][2] = {};
#pragma unroll
    for (int ks = 0; ks < 9; ++ks) {
        int ky = ks / 3, kx = ks - ky*3;
        half8 af0 = *(const half8*)&Wl[m16*296 + ks*32 + quad*8];
        half8 af1 = *(const half8*)&Wl[(16 + m16)*296 + ks*32 + quad*8];
        int px0 = wv*32 + m16;
        half8 bf0 = *(const half8*)&Xl[(ky*130 + px0 + kx)*40 + quad*8];
        half8 bf1 = *(const half8*)&Xl[(ky*130 + px0 + 16 + kx)*40 + quad*8];
        acc[0][0] = __builtin_amdgcn_mfma_f32_16x16x32_f16(af0, bf0, acc[0][0], 0, 0, 0);
        acc[0][1] = __builtin_amdgcn_mfma_f32_16x16x32_f16(af0, bf1, acc[0][1], 0, 0, 0);
        acc[1][0] = __builtin_amdgcn_mfma_f32_16x16x32_f16(af1, bf0, acc[1][0], 0, 0, 0);
        acc[1][1] = __builtin_amdgcn_mfma_f32_16x16x32_f16(af1, bf1, acc[1][1], 0, 0, 0);
    }
    float bo[2][4];
#pragma unroll
    for (int mt = 0; mt < 2; ++mt)
#pragma unroll
        for (int r = 0; r < 4; ++r)
            bo[mt][r] = bias[g*32 + mt*16 + quad*4 + r];
#pragma unroll
    for (int mt = 0; mt < 2; ++mt)
#pragma unroll
        for (int nt = 0; nt < 2; ++nt) {
            int px = w0 + wv*32 + nt*16 + m16;
            int oc = g*32 + mt*16 + quad*4;
            size_t off = ((size_t)((b*128 + h)*256 + px))*128 + oc;
            float rv4[4] = {0.f, 0.f, 0.f, 0.f};
            if (RES) {
                union { f16 h[4]; uint2 v2; } rr;
                rr.v2 = *(const uint2*)(res + off);
#pragma unroll
                for (int r = 0; r < 4; ++r) rv4[r] = (float)rr.h[r];
            }
            union { f16 h[4]; uint2 v2; } ov;
#pragma unroll
            for (int r = 0; r < 4; ++r) {
                float y = acc[mt][nt][r] + bo[mt][r];
                if (LEAKY) y = y > 0.f ? y : 0.1f*y;
                if (RES) y += rv4[r];
                ov.h[r] = (f16)y;
            }
            *(uint2*)(out + off) = ov.v2;
        }
}

// ---------------------------------------------------------------------------
// K4: grouped 1x1 conv (128->64, groups=2) + row-mean subtraction fused.
// Bias cancels under mean-sub (Q - mean(Q)).  Out: f16 [n][i][64] MFMA-ready.
// grid (512 bh, 2 group); 256 threads = w pixel.
// ---------------------------------------------------------------------------
__global__ __launch_bounds__(256) void k_conv1x1m(
    const f16* __restrict__ in, const float* __restrict__ wgt,
    f16* __restrict__ outq)
{
    __shared__ float Wl[32][68];
    __shared__ float Ab[32][260];
    __shared__ float meanS[32];
    int n = blockIdx.x; int g = blockIdx.y; int t = threadIdx.x;
    int lane = t & 63, wv = t >> 6;
    for (int idx = t; idx < 2048; idx += 256) Wl[idx >> 6][idx & 63] = wgt[g*2048 + idx];
    float rv[64];
    const f16* rp = in + ((size_t)n*256 + t)*128 + g*64;
#pragma unroll
    for (int i8 = 0; i8 < 8; ++i8) {
        union { uint4 v4; f16 h[8]; } ld;
        ld.v4 = *(const uint4*)(rp + i8*8);
#pragma unroll
        for (int j = 0; j < 8; ++j) rv[i8*8 + j] = (float)ld.h[j];
    }
    __syncthreads();
    float acc[32];
#pragma unroll
    for (int ol = 0; ol < 32; ++ol) {
        float a = 0.f;
#pragma unroll
        for (int i4 = 0; i4 < 16; ++i4) {
            float4 w4 = *(const float4*)&Wl[ol][i4*4];
            a = fmaf(w4.x, rv[i4*4+0], a);
            a = fmaf(w4.y, rv[i4*4+1], a);
            a = fmaf(w4.z, rv[i4*4+2], a);
            a = fmaf(w4.w, rv[i4*4+3], a);
        }
        acc[ol] = a;
        Ab[ol][t] = a;
    }
    __syncthreads();
#pragma unroll
    for (int k = 0; k < 8; ++k) {
        int o = wv*8 + k;
        float s = Ab[o][lane] + Ab[o][lane+64] + Ab[o][lane+128] + Ab[o][lane+192];
#pragma unroll
        for (int off = 32; off; off >>= 1) s += __shfl_xor(s, off);
        if (lane == 0) meanS[o] = s * (1.0f/256.0f);
    }
    __syncthreads();
    f16* qp = outq + ((size_t)n*256 + t)*64 + g*32;
#pragma unroll
    for (int o8 = 0; o8 < 4; ++o8) {
        union { uint4 v4; f16 h[8]; } pk;
#pragma unroll
        for (int e = 0; e < 8; ++e)
            pk.h[e] = (f16)(acc[o8*8+e] - meanS[o8*8+e]);
        *(uint4*)(qp + o8*8) = pk.v4;
    }
}

// ---------------------------------------------------------------------------
// K5: score S = Q K^T per n via MFMA f16.  Q,K: [n][256][64] f16.
// Writes S[n][i][j] and ST[n][j][i] (both f16).  grid 512; 256 thr.
// ---------------------------------------------------------------------------
__global__ __launch_bounds__(256) void k_score(
    const f16* __restrict__ Q, const f16* __restrict__ K,
    f16* __restrict__ S, f16* __restrict__ ST)
{
    __shared__ f16 Qs[256][72];
    __shared__ f16 Ks[64][72];
    int n = blockIdx.x; int t = threadIdx.x;
    const f16* qg = Q + (size_t)n*16384 + (size_t)t*64;
#pragma unroll
    for (int k = 0; k < 8; ++k)
        *(uint4*)&Qs[t][k*8] = *(const uint4*)(qg + k*8);
    int lane = t & 63, wv = t >> 6;
    int m16 = lane & 15, quad = lane >> 4;
    int m0 = wv*64;
    half8 af[4][2];
    bool afl = false;
    f16* Sn = S + (size_t)n*65536;
    f16* STn = ST + (size_t)n*65536;
    for (int jc = 0; jc < 256; jc += 64) {
        __syncthreads();   // Qs ready (first iter) / Ks consumers done (later)
        {
            int jj = t >> 2, seg = (t & 3) * 16;
            const f16* kg = K + (size_t)n*16384 + (size_t)(jc + jj)*64 + seg;
            *(uint4*)&Ks[jj][seg]     = *(const uint4*)(kg);
            *(uint4*)&Ks[jj][seg + 8] = *(const uint4*)(kg + 8);
        }
        __syncthreads();
        if (!afl) {
            afl = true;
#pragma unroll
            for (int mt = 0; mt < 4; ++mt)
#pragma unroll
                for (int kk = 0; kk < 2; ++kk)
                    af[mt][kk] = *(const half8*)&Qs[m0 + mt*16 + m16][kk*32 + quad*8];
        }
        half8 bf[4][2];
#pragma unroll
        for (int nt = 0; nt < 4; ++nt)
#pragma unroll
            for (int kk = 0; kk < 2; ++kk)
                bf[nt][kk] = *(const half8*)&Ks[nt*16 + m16][kk*32 + quad*8];
        f32x4 acc[4][4] = {};
#pragma unroll
        for (int mt = 0; mt < 4; ++mt)
#pragma unroll
            for (int nt = 0; nt < 4; ++nt) {
                acc[mt][nt] = __builtin_amdgcn_mfma_f32_16x16x32_f16(af[mt][0], bf[nt][0], acc[mt][nt], 0, 0, 0);
                acc[mt][nt] = __builtin_amdgcn_mfma_f32_16x16x32_f16(af[mt][1], bf[nt][1], acc[mt][nt], 0, 0, 0);
            }
#pragma unroll
        for (int mt = 0; mt < 4; ++mt)
#pragma unroll
            for (int nt = 0; nt < 4; ++nt) {
                int i = m0 + mt*16 + quad*4;
                int j = jc + nt*16 + m16;
                union { f16 h[4]; uint2 u2; } pv;
#pragma unroll
                for (int r = 0; r < 4; ++r) {
                    f16 vv = (f16)acc[mt][nt][r];
                    Sn[(size_t)(i + r)*256 + j] = vv;
                    pv.h[r] = vv;
                }
                *(uint2*)&STn[(size_t)j*256 + i] = pv.u2;   // 4 consecutive i
            }
    }
}

// ---------------------------------------------------------------------------
// K6: softmax stats.  grid (512 n, 2 half): rows r0..r0+127.
// Row stats exact (full row in block); col stats as online partials per half.
// ---------------------------------------------------------------------------
__global__ __launch_bounds__(256) void k_stats(
    const f16* __restrict__ S, float* __restrict__ rmax, float* __restrict__ rsumi,
    float* __restrict__ cpm, float* __restrict__ cps)
{
    __shared__ float red[4], red2[4];
    int n = blockIdx.x, h2 = blockIdx.y, t = threadIdx.x;
    int r0 = h2*128;
    int lane = t & 63, wid = t >> 6;
    const f16* Sp = S + (size_t)n*65536 + (size_t)r0*256 + t;
    float cm = -1e30f, cs = 0.f;
    float cur = (float)Sp[0];
    for (int s = 0; s < 128; ++s) {
        float nxt = (s < 127) ? (float)Sp[(size_t)(s+1)*256] : 0.f;
        float mx = cur;
#pragma unroll
        for (int off = 32; off; off >>= 1) mx = fmaxf(mx, __shfl_xor(mx, off));
        if (lane == 0) red[wid] = mx;
        __syncthreads();
        mx = fmaxf(fmaxf(red[0], red[1]), fmaxf(red[2], red[3]));
        float e = __expf(cur - mx);
#pragma unroll
        for (int off = 32; off; off >>= 1) e += __shfl_xor(e, off);
        if (lane == 0) red2[wid] = e;
        __syncthreads();
        if (t == 0) {
            float sum = red2[0] + red2[1] + red2[2] + red2[3];
            rmax[n*256 + r0 + s] = mx;
            rsumi[n*256 + r0 + s] = 1.0f / sum;
        }
        float nm = fmaxf(cm, cur);
        cs = cs*__expf(cm - nm) + __expf(cur - nm);
        cm = nm;
        cur = nxt;
    }
    cpm[(n*2 + h2)*256 + t] = cm;
    cps[(n*2 + h2)*256 + t] = cs;
}

// ---------------------------------------------------------------------------
// K7: fused V_l + V_r in one S stream.  grid (512 n, 2 half).
// Streams rows r0-2..r0+129 with 5-row register window + LDS halo row.
// Also writes merged cmax/csumi (h2==0).
// ---------------------------------------------------------------------------
__global__ __launch_bounds__(256) void k_v(
    const f16* __restrict__ S, const float* __restrict__ rmax, const float* __restrict__ rsumi,
    const float* __restrict__ cpm, const float* __restrict__ cps,
    float* __restrict__ cmax, float* __restrict__ csumi,
    float* __restrict__ Vl, float* __restrict__ Vr0, float* __restrict__ Vr1)
{
    __shared__ float cmS[256], ciS[256];
    __shared__ float rmS[132], riS[132];
    __shared__ float rowbuf[260];
    __shared__ float red[4];
    int n = blockIdx.x, h2 = blockIdx.y, t = threadIdx.x;
    int r0 = h2*128;
    int lane = t & 63, wid = t >> 6;
    float m0 = cpm[(n*2+0)*256+t], s0 = cps[(n*2+0)*256+t];
    float m1 = cpm[(n*2+1)*256+t], s1 = cps[(n*2+1)*256+t];
    float cm = fmaxf(m0, m1);
    float cs = s0*__expf(m0-cm) + s1*__expf(m1-cm);
    float ci = 1.0f/cs;
    cmS[t] = cm; ciS[t] = ci;
    if (h2 == 0) { cmax[n*256+t] = cm; csumi[n*256+t] = ci; }
    if (t < 132) {
        int rr = r0 - 2 + t;
        if ((unsigned)rr < 256u) { rmS[t] = rmax[n*256+rr]; riS[t] = rsumi[n*256+rr]; }
        else { rmS[t] = 0.f; riS[t] = 0.f; }
    }
    if (t < 2) { rowbuf[t] = 0.f; rowbuf[258+t] = 0.f; }
    __syncthreads();
    float cmr[5], cir[5];
#pragma unroll
    for (int d = 0; d < 5; ++d) {
        int idx = t + d - 2;
        if ((unsigned)idx < 256u) { cmr[d] = cmS[idx]; cir[d] = ciS[idx]; }
        else { cmr[d] = 0.f; cir[d] = 0.f; }
    }
    const f16* Sp = S + (size_t)n*65536 + t;
    float w0=0.f, w1=0.f, w2=0.f, w3=0.f, w4=0.f;
    float vr = 0.f;
    int rr0 = r0 - 2;
    float pf = ((unsigned)rr0 < 256u) ? (float)Sp[(size_t)rr0*256] : 0.f;
    for (int s = 0; s < 132; ++s) {
        float cur = pf;
        int rn = rr0 + s + 1;
        pf = ((unsigned)rn < 256u) ? (float)Sp[(size_t)rn*256] : 0.f;
        w0=w1; w1=w2; w2=w3; w3=w4; w4=cur;
        rowbuf[2 + t] = cur;
        __syncthreads();
        if (s >= 2 && s <= 129) {
            float pr = __expf(cur - rmS[s]) * riS[s];
            float relaxc = 0.f;
#pragma unroll
            for (int d = 0; d < 5; ++d)
                relaxc += __expf(rowbuf[t + d] - cmr[d]) * cir[d];
            vr = fmaf(relaxc, pr, vr);
        }
        if (s >= 4) {
            float relaxr = __expf(w0 - rmS[s-4])*riS[s-4]
                         + __expf(w1 - rmS[s-3])*riS[s-3]
                         + __expf(w2 - rmS[s-2])*riS[s-2]
                         + __expf(w3 - rmS[s-1])*riS[s-1]
                         + __expf(w4 - rmS[s  ])*riS[s  ];
            float pl = relaxr * __expf(w2 - cmS[t]) * ciS[t];
#pragma unroll
            for (int off = 32; off; off >>= 1) pl += __shfl_xor(pl, off);
            if (lane == 0) red[wid] = pl;
        }
        __syncthreads();
        if (s >= 4 && t == 0)
            Vl[n*256 + r0 + s - 4] = red[0] + red[1] + red[2] + red[3];
    }
    float* Vrp = h2 ? Vr1 : Vr0;
    Vrp[n*256 + t] = vr;
}

// ---------------------------------------------------------------------------
// K8: out = xP*(1-t) + (P @ xB)*t,  t = tanh(5 V).   MFMA f16.
// P rows from P16 (S for left / ST for right) with exp(v - sm[row])*si[row].
// grid 512 n; 256 thr; LDS 46KB.
// ---------------------------------------------------------------------------
__global__ __launch_bounds__(256) void k_out(
    const f16* __restrict__ P16, const float* __restrict__ sm, const float* __restrict__ si,
    const float* __restrict__ V1, const float* __restrict__ V2,
    const float* __restrict__ xB, const float* __restrict__ xP,
    float* __restrict__ outp)
{
    __shared__ f16 Pl[256][72];
    __shared__ f16 Xl[64][72];
    int n = blockIdx.x; int b = n >> 7; int h = n & 127;
    int t = threadIdx.x;
    int lane = t & 63, wv = t >> 6;
    int m16 = lane & 15, quad = lane >> 4;
    float rm = sm[n*256 + t], ri = si[n*256 + t];
    f32x4 acc[4][4] = {};
    for (int kc = 0; kc < 256; kc += 64) {
        const f16* pg = P16 + (size_t)n*65536 + (size_t)t*256 + kc;
#pragma unroll
        for (int k8 = 0; k8 < 8; ++k8) {
            union { uint4 v4; f16 h[8]; } ldu, stu;
            ldu.v4 = *(const uint4*)(pg + k8*8);
#pragma unroll
            for (int e = 0; e < 8; ++e)
                stu.h[e] = (f16)(__expf((float)ldu.h[e] - rm) * ri);
            *(uint4*)&Pl[t][k8*8] = stu.v4;
        }
        {
            int c = t >> 2, j0 = (t & 3) * 16;
            const float* xg = xB + (((size_t)(b*64 + c)*128 + h) << 8) + kc + j0;
            union { uint4 v4; f16 h[8]; } xu0, xu1;
#pragma unroll
            for (int e = 0; e < 8; ++e) xu0.h[e] = (f16)xg[e];
#pragma unroll
            for (int e = 0; e < 8; ++e) xu1.h[e] = (f16)xg[8 + e];
            *(uint4*)&Xl[c][j0]     = xu0.v4;
            *(uint4*)&Xl[c][j0 + 8] = xu1.v4;
        }
        __syncthreads();
        int mbase = wv*64;
        half8 a0[4][2], b0[4][2];
#pragma unroll
        for (int mt = 0; mt < 4; ++mt)
#pragma unroll
            for (int kk = 0; kk < 2; ++kk)
                a0[mt][kk] = *(const half8*)&Pl[mbase + mt*16 + m16][kk*32 + quad*8];
#pragma unroll
        for (int nt = 0; nt < 4; ++nt)
#pragma unroll
            for (int kk = 0; kk < 2; ++kk)
                b0[nt][kk] = *(const half8*)&Xl[nt*16 + m16][kk*32 + quad*8];
#pragma unroll
        for (int mt = 0; mt < 4; ++mt)
#pragma unroll
            for (int nt = 0; nt < 4; ++nt) {
                acc[mt][nt] = __builtin_amdgcn_mfma_f32_16x16x32_f16(a0[mt][0], b0[nt][0], acc[mt][nt], 0, 0, 0);
                acc[mt][nt] = __builtin_amdgcn_mfma_f32_16x16x32_f16(a0[mt][1], b0[nt][1], acc[mt][nt], 0, 0, 0);
            }
        __syncthreads();
    }
#pragma unroll
    for (int mt = 0; mt < 4; ++mt) {
        int i0 = wv*64 + mt*16 + quad*4;
        float v4[4];
        *(float4*)v4 = *(const float4*)&V1[n*256 + i0];
        if (V2) {
            float u4[4]; *(float4*)u4 = *(const float4*)&V2[n*256 + i0];
#pragma unroll
            for (int r = 0; r < 4; ++r) v4[r] += u4[r];
        }
        float tv[4];
#pragma unroll
        for (int r = 0; r < 4; ++r) tv[r] = tanhf(5.f*v4[r]);
#pragma unroll
        for (int nt = 0; nt < 4; ++nt) {
            int c = nt*16 + m16;
            size_t base = (((size_t)(b*64 + c)*128 + h) << 8) + i0;
            float xp4[4]; *(float4*)xp4 = *(const float4*)&xP[base];
            float o4[4];
#pragma unroll
            for (int r = 0; r < 4; ++r)
                o4[r] = xp4[r]*(1.f - tv[r]) + acc[mt][nt][r]*tv[r];
            *(float4*)&outp[base] = *(float4*)o4;
        }
    }
}

// ---------------------------------------------------------------------------
extern "C" void kernel_launch(void* const* d_in, const int* in_sizes, int n_in,
                              void* d_out, int out_size, void* d_ws, size_t ws_size,
                              hipStream_t stream)
{
    const float* x_left  = (const float*)d_in[0];
    const float* x_right = (const float*)d_in[1];
    const float* conv1_w = (const float*)d_in[2];
    const float* conv1_b = (const float*)d_in[3];
    const float* conv2_w = (const float*)d_in[4];
    const float* conv2_b = (const float*)d_in[5];
    const float* bn_g    = (const float*)d_in[6];
    const float* bn_b    = (const float*)d_in[7];
    const float* bn_m    = (const float*)d_in[8];
    const float* bn_v    = (const float*)d_in[9];
    const float* rb_w1   = (const float*)d_in[10];
    const float* rb_b1   = (const float*)d_in[11];
    const float* rb_w2   = (const float*)d_in[12];
    const float* rb_b2   = (const float*)d_in[13];
    const float* bq_w    = (const float*)d_in[14];
    const float* bs_w    = (const float*)d_in[16];

    f16* W16 = (f16*)d_ws;
    // f16 regions (element offsets). u/y1 alias S; r aliases ST (all dead by then).
    f16* u  = W16;                       // 16,777,216 els
    f16* y1 = W16 + 16777216;            // 16,777,216
    f16* r  = W16 + 33554432;            // 16,777,216
    f16* S  = W16;                       // 33,554,432 (aliases u+y1)
    f16* ST = W16 + 33554432;            // 33,554,432 (aliases r + fresh)
    f16* Qh = W16 + 67108864;            //  8,388,608
    f16* Kh = W16 + 75497472;            //  8,388,608
    float* F32  = (float*)(W16 + 83886080);
    float* rmax  = F32;                  // 131,072
    float* rsumi = F32 + 131072;
    float* cpm   = F32 + 262144;         // 262,144
    float* cps   = F32 + 524288;         // 262,144
    float* cmax  = F32 + 786432;         // 131,072
    float* csumi = F32 + 917504;         // 131,072
    float* Vl    = F32 + 1048576;        // 131,072
    float* Vr0   = F32 + 1179648;        // 131,072
    float* Vr1   = F32 + 1310720;        // 131,072

    float* out_left  = (float*)d_out;
    float* out_right = (float*)d_out + 8388608;

    // ---- left branch -> Q ----
    k_catbn_m<<<NN, 256, 0, stream>>>(x_left, conv1_w, conv1_b, bn_g, bn_b, bn_m, bn_v, u);
    k_conv3m<true,  false><<<dim3(NN, 4, 2), 256, 0, stream>>>(u, rb_w1, rb_b1, nullptr, y1);
    k_conv3m<false, true ><<<dim3(NN, 4, 2), 256, 0, stream>>>(y1, rb_w2, rb_b2, u, r);
    k_conv1x1m<<<dim3(NN, 2), 256, 0, stream>>>(r, bq_w, Qh);

    // ---- right branch -> K ----
    k_catbn_m<<<NN, 256, 0, stream>>>(x_right, conv2_w, conv2_b, bn_g, bn_b, bn_m, bn_v, u);
    k_conv3m<true,  false><<<dim3(NN, 4, 2), 256, 0, stream>>>(u, rb_w1, rb_b1, nullptr, y1);
    k_conv3m<false, true ><<<dim3(NN, 4, 2), 256, 0, stream>>>(y1, rb_w2, rb_b2, u, r);
    k_conv1x1m<<<dim3(NN, 2), 256, 0, stream>>>(r, bs_w, Kh);

    // ---- attention ----
    k_score<<<NN, 256, 0, stream>>>(Qh, Kh, S, ST);
    k_stats<<<dim3(NN, 2), 256, 0, stream>>>(S, rmax, rsumi, cpm, cps);
    k_v<<<dim3(NN, 2), 256, 0, stream>>>(S, rmax, rsumi, cpm, cps, cmax, csumi, Vl, Vr0, Vr1);
    k_out<<<NN, 256, 0, stream>>>(S,  rmax, rsumi, Vl,  nullptr, x_right, x_left,  out_left);
    k_out<<<NN, 256, 0, stream>>>(ST, cmax, csumi, Vr0, Vr1,     x_left,  x_right, out_right);
}

// Round 5
// 918.171 us; speedup vs baseline: 3.9888x; 1.0333x over previous
//
#include <hip/hip_runtime.h>
#include <math.h>

// Problem constants
#define BB 4
#define CC 64
#define C2 128
#define HH 128
#define WW 256
#define NN (BB*HH)          // 512 row-pairs
#define EPSBN 1e-5f

typedef _Float16 f16;
typedef _Float16 half8 __attribute__((ext_vector_type(8)));
typedef float f32x4 __attribute__((ext_vector_type(4)));

// ---------------------------------------------------------------------------
// K1: fused 1x1 conv (64->64) + concat + batchnorm -> u (channel-last f16)
// via MFMA 16x16x32 f16.  u[n][px][128].  grid 512 = (b,h); 256 thr = 4 waves.
// ---------------------------------------------------------------------------
__global__ __launch_bounds__(256) void k_catbn_m(
    const float* __restrict__ x, const float* __restrict__ cw, const float* __restrict__ cb,
    const float* __restrict__ g, const float* __restrict__ bb_, const float* __restrict__ m,
    const float* __restrict__ v, f16* __restrict__ u)
{
    __shared__ f16 Xl[256][72];   // [px][ic]
    __shared__ f16 Wl[64][72];    // [oc][ic]
    __shared__ float sS[64], sT[64], sS2[64], sT2[64];
    int n = blockIdx.x; int b = n >> 7; int h = n & 127; int t = threadIdx.x;
    for (int p = t; p < 2048; p += 256) {
        int idx = p * 2; int o = idx >> 6, i = idx & 63;
        union { f16 h[2]; unsigned int u1; } pr;
        pr.h[0] = (f16)cw[idx]; pr.h[1] = (f16)cw[idx + 1];
        *(unsigned int*)&Wl[o][i] = pr.u1;
    }
    if (t < 64) {
        float inv = rsqrtf(v[t] + EPSBN); float s = g[t] * inv;
        sS[t] = s; sT[t] = bb_[t] + s * (cb[t] - m[t]);
        float inv2 = rsqrtf(v[t + 64] + EPSBN); float s2 = g[t + 64] * inv2;
        sS2[t] = s2; sT2[t] = bb_[t + 64] - s2 * m[t + 64];
    }
    __syncthreads();
    f16* up = u + ((size_t)(n*256 + t)) * 128;
    for (int c8 = 0; c8 < 8; ++c8) {
        float xv8[8];
#pragma unroll
        for (int j = 0; j < 8; ++j)
            xv8[j] = x[(((b*64 + c8*8 + j)*128 + h) << 8) + t];
        union { f16 h[8]; uint4 v4; } pk;
#pragma unroll
        for (int j = 0; j < 8; ++j) {
            int c = c8*8 + j;
            pk.h[j] = (f16)(sS2[c]*xv8[j] + sT2[c]);
        }
        *(uint4*)(up + 64 + c8*8) = pk.v4;
#pragma unroll
        for (int j2 = 0; j2 < 4; ++j2) {
            union { f16 h[2]; unsigned int u1; } q;
            q.h[0] = (f16)xv8[j2*2]; q.h[1] = (f16)xv8[j2*2 + 1];
            *(unsigned int*)&Xl[t][c8*8 + j2*2] = q.u1;
        }
    }
    __syncthreads();
    int lane = t & 63, wv = t >> 6;
    int m16 = lane & 15, quad = lane >> 4;
    half8 af[4][2], bf[4][2];
#pragma unroll
    for (int mt = 0; mt < 4; ++mt)
#pragma unroll
        for (int kk = 0; kk < 2; ++kk)
            af[mt][kk] = *(const half8*)&Wl[mt*16 + m16][kk*32 + quad*8];
#pragma unroll
    for (int nt = 0; nt < 4; ++nt)
#pragma unroll
        for (int kk = 0; kk < 2; ++kk)
            bf[nt][kk] = *(const half8*)&Xl[wv*64 + nt*16 + m16][kk*32 + quad*8];
    f32x4 acc[4][4] = {};
#pragma unroll
    for (int mt = 0; mt < 4; ++mt)
#pragma unroll
        for (int nt = 0; nt < 4; ++nt) {
            acc[mt][nt] = __builtin_amdgcn_mfma_f32_16x16x32_f16(af[mt][0], bf[nt][0], acc[mt][nt], 0, 0, 0);
            acc[mt][nt] = __builtin_amdgcn_mfma_f32_16x16x32_f16(af[mt][1], bf[nt][1], acc[mt][nt], 0, 0, 0);
        }
#pragma unroll
    for (int mt = 0; mt < 4; ++mt) {
        int ocb = mt*16 + quad*4;
        float s4[4], t4[4];
        *(float4*)s4 = *(const float4*)&sS[ocb];
        *(float4*)t4 = *(const float4*)&sT[ocb];
#pragma unroll
        for (int nt = 0; nt < 4; ++nt) {
            int px = wv*64 + nt*16 + m16;
            union { f16 h[4]; uint2 u2; } ov;
#pragma unroll
            for (int r = 0; r < 4; ++r)
                ov.h[r] = (f16)(s4[r]*acc[mt][nt][r] + t4[r]);
            *(uint2*)(u + ((size_t)(n*256 + px))*128 + ocb) = ov.u2;
        }
    }
}

// ---------------------------------------------------------------------------
// K2/K3: grouped 3x3 conv via implicit-GEMM f16 MFMA 16x16x32.
// ---------------------------------------------------------------------------
template<bool LEAKY, bool RES>
__global__ __launch_bounds__(256) void k_conv3m(
    const f16* __restrict__ in, const float* __restrict__ wgt,
    const float* __restrict__ bias, const f16* __restrict__ res,
    f16* __restrict__ out)
{
    __shared__ f16 Wl[32*296];    // [mo][k] stride 296
    __shared__ f16 Xl[3*130*40];  // [row][px][ic] px-stride 40
    int n = blockIdx.x; int b = n >> 7; int h = n & 127;
    int g = blockIdx.y; int w0 = blockIdx.z * 128;
    int t = threadIdx.x;
    for (int p = t; p < 4608; p += 256) {
        int kidx = p * 2;
        int mo = kidx / 288; int kr = kidx - mo*288;
        int ic = kr & 31; int ks = kr >> 5;
        int gb = ((g*32 + mo)*32 + ic)*9 + ks;
        union { f16 h[2]; unsigned int u; } pr;
        pr.h[0] = (f16)wgt[gb];
        pr.h[1] = (f16)wgt[gb + 9];
        *(unsigned int*)&Wl[mo*296 + kr] = pr.u;
    }
    for (int idx = t; idx < 1560; idx += 256) {
        int r = idx / 520; int rem = idx - r*520; int p = rem >> 2; int q = rem & 3;
        int hr = h + r - 1; int wg = w0 + p - 1;
        uint4 val = make_uint4(0,0,0,0);
        if (p < 130 && (unsigned)wg < 256u && (unsigned)hr < 128u)
            val = *(const uint4*)(in + ((size_t)((b*128 + hr)*256 + wg))*128 + g*32 + q*8);
        if (p < 130)
            *(uint4*)&Xl[(r*130 + p)*40 + q*8] = val;
    }
    __syncthreads();
    int lane = t & 63, wv = t >> 6;
    int m16 = lane & 15, quad = lane >> 4;
    f32x4 acc[2][2] = {};
#pragma unroll
    for (int ks = 0; ks < 9; ++ks) {
        int ky = ks / 3, kx = ks - ky*3;
        half8 af0 = *(const half8*)&Wl[m16*296 + ks*32 + quad*8];
        half8 af1 = *(const half8*)&Wl[(16 + m16)*296 + ks*32 + quad*8];
        int px0 = wv*32 + m16;
        half8 bf0 = *(const half8*)&Xl[(ky*130 + px0 + kx)*40 + quad*8];
        half8 bf1 = *(const half8*)&Xl[(ky*130 + px0 + 16 + kx)*40 + quad*8];
        acc[0][0] = __builtin_amdgcn_mfma_f32_16x16x32_f16(af0, bf0, acc[0][0], 0, 0, 0);
        acc[0][1] = __builtin_amdgcn_mfma_f32_16x16x32_f16(af0, bf1, acc[0][1], 0, 0, 0);
        acc[1][0] = __builtin_amdgcn_mfma_f32_16x16x32_f16(af1, bf0, acc[1][0], 0, 0, 0);
        acc[1][1] = __builtin_amdgcn_mfma_f32_16x16x32_f16(af1, bf1, acc[1][1], 0, 0, 0);
    }
    float bo[2][4];
#pragma unroll
    for (int mt = 0; mt < 2; ++mt)
#pragma unroll
        for (int r = 0; r < 4; ++r)
            bo[mt][r] = bias[g*32 + mt*16 + quad*4 + r];
#pragma unroll
    for (int mt = 0; mt < 2; ++mt)
#pragma unroll
        for (int nt = 0; nt < 2; ++nt) {
            int px = w0 + wv*32 + nt*16 + m16;
            int oc = g*32 + mt*16 + quad*4;
            size_t off = ((size_t)((b*128 + h)*256 + px))*128 + oc;
            float rv4[4] = {0.f, 0.f, 0.f, 0.f};
            if (RES) {
                union { f16 h[4]; uint2 v2; } rr;
                rr.v2 = *(const uint2*)(res + off);
#pragma unroll
                for (int r = 0; r < 4; ++r) rv4[r] = (float)rr.h[r];
            }
            union { f16 h[4]; uint2 v2; } ov;
#pragma unroll
            for (int r = 0; r < 4; ++r) {
                float y = acc[mt][nt][r] + bo[mt][r];
                if (LEAKY) y = y > 0.f ? y : 0.1f*y;
                if (RES) y += rv4[r];
                ov.h[r] = (f16)y;
            }
            *(uint2*)(out + off) = ov.v2;
        }
}

// ---------------------------------------------------------------------------
// K4: grouped 1x1 conv (128->64, groups=2) + row-mean subtraction fused.
// ---------------------------------------------------------------------------
__global__ __launch_bounds__(256) void k_conv1x1m(
    const f16* __restrict__ in, const float* __restrict__ wgt,
    f16* __restrict__ outq)
{
    __shared__ float Wl[32][68];
    __shared__ float Ab[32][260];
    __shared__ float meanS[32];
    int n = blockIdx.x; int g = blockIdx.y; int t = threadIdx.x;
    int lane = t & 63, wv = t >> 6;
    for (int idx = t; idx < 2048; idx += 256) Wl[idx >> 6][idx & 63] = wgt[g*2048 + idx];
    float rv[64];
    const f16* rp = in + ((size_t)n*256 + t)*128 + g*64;
#pragma unroll
    for (int i8 = 0; i8 < 8; ++i8) {
        union { uint4 v4; f16 h[8]; } ld;
        ld.v4 = *(const uint4*)(rp + i8*8);
#pragma unroll
        for (int j = 0; j < 8; ++j) rv[i8*8 + j] = (float)ld.h[j];
    }
    __syncthreads();
    float acc[32];
#pragma unroll
    for (int ol = 0; ol < 32; ++ol) {
        float a = 0.f;
#pragma unroll
        for (int i4 = 0; i4 < 16; ++i4) {
            float4 w4 = *(const float4*)&Wl[ol][i4*4];
            a = fmaf(w4.x, rv[i4*4+0], a);
            a = fmaf(w4.y, rv[i4*4+1], a);
            a = fmaf(w4.z, rv[i4*4+2], a);
            a = fmaf(w4.w, rv[i4*4+3], a);
        }
        acc[ol] = a;
        Ab[ol][t] = a;
    }
    __syncthreads();
#pragma unroll
    for (int k = 0; k < 8; ++k) {
        int o = wv*8 + k;
        float s = Ab[o][lane] + Ab[o][lane+64] + Ab[o][lane+128] + Ab[o][lane+192];
#pragma unroll
        for (int off = 32; off; off >>= 1) s += __shfl_xor(s, off);
        if (lane == 0) meanS[o] = s * (1.0f/256.0f);
    }
    __syncthreads();
    f16* qp = outq + ((size_t)n*256 + t)*64 + g*32;
#pragma unroll
    for (int o8 = 0; o8 < 4; ++o8) {
        union { uint4 v4; f16 h[8]; } pk;
#pragma unroll
        for (int e = 0; e < 8; ++e)
            pk.h[e] = (f16)(acc[o8*8+e] - meanS[o8*8+e]);
        *(uint4*)(qp + o8*8) = pk.v4;
    }
}

// ---------------------------------------------------------------------------
// K5: score S = Q K^T per n via MFMA f16.  Writes S and ST (f16).
// ---------------------------------------------------------------------------
__global__ __launch_bounds__(256) void k_score(
    const f16* __restrict__ Q, const f16* __restrict__ K,
    f16* __restrict__ S, f16* __restrict__ ST)
{
    __shared__ f16 Qs[256][72];
    __shared__ f16 Ks[64][72];
    int n = blockIdx.x; int t = threadIdx.x;
    const f16* qg = Q + (size_t)n*16384 + (size_t)t*64;
#pragma unroll
    for (int k = 0; k < 8; ++k)
        *(uint4*)&Qs[t][k*8] = *(const uint4*)(qg + k*8);
    int lane = t & 63, wv = t >> 6;
    int m16 = lane & 15, quad = lane >> 4;
    int m0 = wv*64;
    half8 af[4][2];
    bool afl = false;
    f16* Sn = S + (size_t)n*65536;
    f16* STn = ST + (size_t)n*65536;
    for (int jc = 0; jc < 256; jc += 64) {
        __syncthreads();
        {
            int jj = t >> 2, seg = (t & 3) * 16;
            const f16* kg = K + (size_t)n*16384 + (size_t)(jc + jj)*64 + seg;
            *(uint4*)&Ks[jj][seg]     = *(const uint4*)(kg);
            *(uint4*)&Ks[jj][seg + 8] = *(const uint4*)(kg + 8);
        }
        __syncthreads();
        if (!afl) {
            afl = true;
#pragma unroll
            for (int mt = 0; mt < 4; ++mt)
#pragma unroll
                for (int kk = 0; kk < 2; ++kk)
                    af[mt][kk] = *(const half8*)&Qs[m0 + mt*16 + m16][kk*32 + quad*8];
        }
        half8 bf[4][2];
#pragma unroll
        for (int nt = 0; nt < 4; ++nt)
#pragma unroll
            for (int kk = 0; kk < 2; ++kk)
                bf[nt][kk] = *(const half8*)&Ks[nt*16 + m16][kk*32 + quad*8];
        f32x4 acc[4][4] = {};
#pragma unroll
        for (int mt = 0; mt < 4; ++mt)
#pragma unroll
            for (int nt = 0; nt < 4; ++nt) {
                acc[mt][nt] = __builtin_amdgcn_mfma_f32_16x16x32_f16(af[mt][0], bf[nt][0], acc[mt][nt], 0, 0, 0);
                acc[mt][nt] = __builtin_amdgcn_mfma_f32_16x16x32_f16(af[mt][1], bf[nt][1], acc[mt][nt], 0, 0, 0);
            }
#pragma unroll
        for (int mt = 0; mt < 4; ++mt)
#pragma unroll
            for (int nt = 0; nt < 4; ++nt) {
                int i = m0 + mt*16 + quad*4;
                int j = jc + nt*16 + m16;
                union { f16 h[4]; uint2 u2; } pv;
#pragma unroll
                for (int r = 0; r < 4; ++r) {
                    f16 vv = (f16)acc[mt][nt][r];
                    Sn[(size_t)(i + r)*256 + j] = vv;
                    pv.h[r] = vv;
                }
                *(uint2*)&STn[(size_t)j*256 + i] = pv.u2;
            }
    }
}

// ---------------------------------------------------------------------------
// K6: softmax stats, barrier-free row reductions via wave partials.
// grid (512 n, 2 half).  Row stats for rows r0..r0+127; col online partials.
// ---------------------------------------------------------------------------
__global__ __launch_bounds__(256) void k_stats(
    const f16* __restrict__ S, float* __restrict__ rmax, float* __restrict__ rsumi,
    float* __restrict__ cpm, float* __restrict__ cps)
{
    __shared__ float Mp[4][128], Ep[4][128];
    int n = blockIdx.x, h2 = blockIdx.y, t = threadIdx.x;
    int r0 = h2*128;
    int lane = t & 63, wv = t >> 6;
    const f16* Sp = S + (size_t)n*65536 + (size_t)r0*256 + t;
    float cm = -1e30f, cs = 0.f;
    float cur = (float)Sp[0];
    for (int s = 0; s < 128; ++s) {
        float nxt = (s < 127) ? (float)Sp[(size_t)(s+1)*256] : 0.f;
        float wm = cur;
#pragma unroll
        for (int off = 32; off; off >>= 1) wm = fmaxf(wm, __shfl_xor(wm, off));
        float e = __expf(cur - wm);
#pragma unroll
        for (int off = 32; off; off >>= 1) e += __shfl_xor(e, off);
        if (lane == 0) { Mp[wv][s] = wm; Ep[wv][s] = e; }
        float nm = fmaxf(cm, cur);
        cs = cs*__expf(cm - nm) + __expf(cur - nm);
        cm = nm;
        cur = nxt;
    }
    cpm[(n*2 + h2)*256 + t] = cm;
    cps[(n*2 + h2)*256 + t] = cs;
    __syncthreads();
    if (t < 128) {
        float m0 = Mp[0][t], m1 = Mp[1][t], m2 = Mp[2][t], m3 = Mp[3][t];
        float mx = fmaxf(fmaxf(m0, m1), fmaxf(m2, m3));
        float sum = Ep[0][t]*__expf(m0 - mx) + Ep[1][t]*__expf(m1 - mx)
                  + Ep[2][t]*__expf(m2 - mx) + Ep[3][t]*__expf(m3 - mx);
        rmax[n*256 + r0 + t] = mx;
        rsumi[n*256 + r0 + t] = 1.0f / sum;
    }
}

// ---------------------------------------------------------------------------
// K7: fused V_l + V_r, barrier-free streaming.  grid (512 n, 2 half).
// Horizontal B-window via intra-wave shuffles (edge lanes compute halo cols);
// V_l wave partials -> LDS -> one final barrier.
// ---------------------------------------------------------------------------
__global__ __launch_bounds__(256) void k_v(
    const f16* __restrict__ S, const float* __restrict__ rmax, const float* __restrict__ rsumi,
    const float* __restrict__ cpm, const float* __restrict__ cps,
    float* __restrict__ cmax, float* __restrict__ csumi,
    float* __restrict__ Vl, float* __restrict__ Vr0, float* __restrict__ Vr1)
{
    __shared__ float rmS[132], riS[132];
    __shared__ float Vlp[4][128];
    int n = blockIdx.x, h2 = blockIdx.y, t = threadIdx.x;
    int r0 = h2*128;
    int lane = t & 63, wv = t >> 6;
    // merged column stats (per own column t)
    float m0 = cpm[(n*2+0)*256+t], s0 = cps[(n*2+0)*256+t];
    float m1 = cpm[(n*2+1)*256+t], s1 = cps[(n*2+1)*256+t];
    float cm = fmaxf(m0, m1);
    float ci = 1.0f/(s0*__expf(m0-cm) + s1*__expf(m1-cm));
    if (h2 == 0) { cmax[n*256+t] = cm; csumi[n*256+t] = ci; }
    // halo column for edge lanes
    int hcol = -1;
    if (lane == 0) hcol = wv*64 - 2;
    else if (lane == 1) hcol = wv*64 - 1;
    else if (lane == 62) hcol = wv*64 + 64;
    else if (lane == 63) hcol = wv*64 + 65;
    bool hvalid = (hcol >= 0) && (hcol < 256);
    float hcm = 0.f, hci = 0.f;
    if (hvalid) {
        float hm0 = cpm[(n*2+0)*256+hcol], hs0 = cps[(n*2+0)*256+hcol];
        float hm1 = cpm[(n*2+1)*256+hcol], hs1 = cps[(n*2+1)*256+hcol];
        hcm = fmaxf(hm0, hm1);
        hci = 1.0f/(hs0*__expf(hm0-hcm) + hs1*__expf(hm1-hcm));
    }
    if (t < 132) {
        int rr = r0 - 2 + t;
        bool ok = (unsigned)rr < 256u;
        rmS[t] = ok ? rmax[n*256+rr] : 0.f;
        riS[t] = ok ? rsumi[n*256+rr] : 0.f;
    }
    __syncthreads();
    const f16* Sp = S + (size_t)n*65536;
    int rr0 = r0 - 2;
    float pf = 0.f, pfh = 0.f;
    if ((unsigned)rr0 < 256u) {
        pf = (float)Sp[(size_t)rr0*256 + t];
        if (hvalid) pfh = (float)Sp[(size_t)rr0*256 + hcol];
    }
    float a0=0.f, a1=0.f, a2=0.f, a3=0.f, a4=0.f;
    float bd1=0.f, bd2=0.f;
    float vr = 0.f;
    for (int s = 0; s < 132; ++s) {
        float cur = pf, curh = pfh;
        int arn = rr0 + s + 1;
        bool okn = (unsigned)arn < 256u;
        pf  = okn ? (float)Sp[(size_t)arn*256 + t] : 0.f;
        pfh = (okn && hvalid) ? (float)Sp[(size_t)arn*256 + hcol] : 0.f;
        float A = __expf(cur - rmS[s]) * riS[s];
        float B = __expf(cur - cm) * ci;
        float Bh = hvalid ? __expf(curh - hcm) * hci : 0.f;
        a0=a1; a1=a2; a2=a3; a3=a4; a4=A;
        // horizontal neighbors of B (intra-wave + halo patches)
        float Bl1 = __shfl(B, (lane+63)&63);
        float Bl2 = __shfl(B, (lane+62)&63);
        float Br1 = __shfl(B, (lane+1)&63);
        float Br2 = __shfl(B, (lane+2)&63);
        float H0  = __shfl(Bh, 0);
        float H1  = __shfl(Bh, 1);
        float H62 = __shfl(Bh, 62);
        float H63 = __shfl(Bh, 63);
        if (lane == 0)  { Bl2 = H0;  Bl1 = H1; }
        if (lane == 1)  { Bl2 = H1; }
        if (lane == 62) { Br2 = H62; }
        if (lane == 63) { Br1 = H62; Br2 = H63; }
        if (s >= 2 && s < 130) {
            float Bwin = Bl2 + Bl1 + B + Br1 + Br2;
            vr = fmaf(Bwin, A, vr);
        }
        if (s >= 4) {
            float pl = (a0 + a1 + a2 + a3 + a4) * bd2;
#pragma unroll
            for (int off = 32; off; off >>= 1) pl += __shfl_xor(pl, off);
            if (lane == 0) Vlp[wv][s-4] = pl;
        }
        bd2 = bd1; bd1 = B;
    }
    (h2 ? Vr1 : Vr0)[n*256 + t] = vr;
    __syncthreads();
    if (t < 128)
        Vl[n*256 + r0 + t] = Vlp[0][t] + Vlp[1][t] + Vlp[2][t] + Vlp[3][t];
}

// ---------------------------------------------------------------------------
// K8: out = xP*(1-t) + (P @ xB)*t,  t = tanh(5 V).   MFMA f16.
// ---------------------------------------------------------------------------
__global__ __launch_bounds__(256) void k_out(
    const f16* __restrict__ P16, const float* __restrict__ sm, const float* __restrict__ si,
    const float* __restrict__ V1, const float* __restrict__ V2,
    const float* __restrict__ xB, const float* __restrict__ xP,
    float* __restrict__ outp)
{
    __shared__ f16 Pl[256][72];
    __shared__ f16 Xl[64][72];
    int n = blockIdx.x; int b = n >> 7; int h = n & 127;
    int t = threadIdx.x;
    int lane = t & 63, wv = t >> 6;
    int m16 = lane & 15, quad = lane >> 4;
    float rm = sm[n*256 + t], ri = si[n*256 + t];
    f32x4 acc[4][4] = {};
    for (int kc = 0; kc < 256; kc += 64) {
        const f16* pg = P16 + (size_t)n*65536 + (size_t)t*256 + kc;
#pragma unroll
        for (int k8 = 0; k8 < 8; ++k8) {
            union { uint4 v4; f16 h[8]; } ldu, stu;
            ldu.v4 = *(const uint4*)(pg + k8*8);
#pragma unroll
            for (int e = 0; e < 8; ++e)
                stu.h[e] = (f16)(__expf((float)ldu.h[e] - rm) * ri);
            *(uint4*)&Pl[t][k8*8] = stu.v4;
        }
        {
            int c = t >> 2, j0 = (t & 3) * 16;
            const float* xg = xB + (((size_t)(b*64 + c)*128 + h) << 8) + kc + j0;
            union { uint4 v4; f16 h[8]; } xu0, xu1;
#pragma unroll
            for (int e = 0; e < 8; ++e) xu0.h[e] = (f16)xg[e];
#pragma unroll
            for (int e = 0; e < 8; ++e) xu1.h[e] = (f16)xg[8 + e];
            *(uint4*)&Xl[c][j0]     = xu0.v4;
            *(uint4*)&Xl[c][j0 + 8] = xu1.v4;
        }
        __syncthreads();
        int mbase = wv*64;
        half8 a0[4][2], b0[4][2];
#pragma unroll
        for (int mt = 0; mt < 4; ++mt)
#pragma unroll
            for (int kk = 0; kk < 2; ++kk)
                a0[mt][kk] = *(const half8*)&Pl[mbase + mt*16 + m16][kk*32 + quad*8];
#pragma unroll
        for (int nt = 0; nt < 4; ++nt)
#pragma unroll
            for (int kk = 0; kk < 2; ++kk)
                b0[nt][kk] = *(const half8*)&Xl[nt*16 + m16][kk*32 + quad*8];
#pragma unroll
        for (int mt = 0; mt < 4; ++mt)
#pragma unroll
            for (int nt = 0; nt < 4; ++nt) {
                acc[mt][nt] = __builtin_amdgcn_mfma_f32_16x16x32_f16(a0[mt][0], b0[nt][0], acc[mt][nt], 0, 0, 0);
                acc[mt][nt] = __builtin_amdgcn_mfma_f32_16x16x32_f16(a0[mt][1], b0[nt][1], acc[mt][nt], 0, 0, 0);
            }
        __syncthreads();
    }
#pragma unroll
    for (int mt = 0; mt < 4; ++mt) {
        int i0 = wv*64 + mt*16 + quad*4;
        float v4[4];
        *(float4*)v4 = *(const float4*)&V1[n*256 + i0];
        if (V2) {
            float u4[4]; *(float4*)u4 = *(const float4*)&V2[n*256 + i0];
#pragma unroll
            for (int r = 0; r < 4; ++r) v4[r] += u4[r];
        }
        float tv[4];
#pragma unroll
        for (int r = 0; r < 4; ++r) tv[r] = tanhf(5.f*v4[r]);
#pragma unroll
        for (int nt = 0; nt < 4; ++nt) {
            int c = nt*16 + m16;
            size_t base = (((size_t)(b*64 + c)*128 + h) << 8) + i0;
            float xp4[4]; *(float4*)xp4 = *(const float4*)&xP[base];
            float o4[4];
#pragma unroll
            for (int r = 0; r < 4; ++r)
                o4[r] = xp4[r]*(1.f - tv[r]) + acc[mt][nt][r]*tv[r];
            *(float4*)&outp[base] = *(float4*)o4;
        }
    }
}

// ---------------------------------------------------------------------------
extern "C" void kernel_launch(void* const* d_in, const int* in_sizes, int n_in,
                              void* d_out, int out_size, void* d_ws, size_t ws_size,
                              hipStream_t stream)
{
    const float* x_left  = (const float*)d_in[0];
    const float* x_right = (const float*)d_in[1];
    const float* conv1_w = (const float*)d_in[2];
    const float* conv1_b = (const float*)d_in[3];
    const float* conv2_w = (const float*)d_in[4];
    const float* conv2_b = (const float*)d_in[5];
    const float* bn_g    = (const float*)d_in[6];
    const float* bn_b    = (const float*)d_in[7];
    const float* bn_m    = (const float*)d_in[8];
    const float* bn_v    = (const float*)d_in[9];
    const float* rb_w1   = (const float*)d_in[10];
    const float* rb_b1   = (const float*)d_in[11];
    const float* rb_w2   = (const float*)d_in[12];
    const float* rb_b2   = (const float*)d_in[13];
    const float* bq_w    = (const float*)d_in[14];
    const float* bs_w    = (const float*)d_in[16];

    f16* W16 = (f16*)d_ws;
    f16* u  = W16;                       // 16,777,216 els
    f16* y1 = W16 + 16777216;            // 16,777,216
    f16* r  = W16 + 33554432;            // 16,777,216
    f16* S  = W16;                       // 33,554,432 (aliases u+y1)
    f16* ST = W16 + 33554432;            // 33,554,432 (aliases r + fresh)
    f16* Qh = W16 + 67108864;            //  8,388,608
    f16* Kh = W16 + 75497472;            //  8,388,608
    float* F32  = (float*)(W16 + 83886080);
    float* rmax  = F32;                  // 131,072
    float* rsumi = F32 + 131072;
    float* cpm   = F32 + 262144;         // 262,144
    float* cps   = F32 + 524288;         // 262,144
    float* cmax  = F32 + 786432;         // 131,072
    float* csumi = F32 + 917504;         // 131,072
    float* Vl    = F32 + 1048576;        // 131,072
    float* Vr0   = F32 + 1179648;        // 131,072
    float* Vr1   = F32 + 1310720;        // 131,072

    float* out_left  = (float*)d_out;
    float* out_right = (float*)d_out + 8388608;

    // ---- left branch -> Q ----
    k_catbn_m<<<NN, 256, 0, stream>>>(x_left, conv1_w, conv1_b, bn_g, bn_b, bn_m, bn_v, u);
    k_conv3m<true,  false><<<dim3(NN, 4, 2), 256, 0, stream>>>(u, rb_w1, rb_b1, nullptr, y1);
    k_conv3m<false, true ><<<dim3(NN, 4, 2), 256, 0, stream>>>(y1, rb_w2, rb_b2, u, r);
    k_conv1x1m<<<dim3(NN, 2), 256, 0, stream>>>(r, bq_w, Qh);

    // ---- right branch -> K ----
    k_catbn_m<<<NN, 256, 0, stream>>>(x_right, conv2_w, conv2_b, bn_g, bn_b, bn_m, bn_v, u);
    k_conv3m<true,  false><<<dim3(NN, 4, 2), 256, 0, stream>>>(u, rb_w1, rb_b1, nullptr, y1);
    k_conv3m<false, true ><<<dim3(NN, 4, 2), 256, 0, stream>>>(y1, rb_w2, rb_b2, u, r);
    k_conv1x1m<<<dim3(NN, 2), 256, 0, stream>>>(r, bs_w, Kh);

    // ---- attention ----
    k_score<<<NN, 256, 0, stream>>>(Qh, Kh, S, ST);
    k_stats<<<dim3(NN, 2), 256, 0, stream>>>(S, rmax, rsumi, cpm, cps);
    k_v<<<dim3(NN, 2), 256, 0, stream>>>(S, rmax, rsumi, cpm, cps, cmax, csumi, Vl, Vr0, Vr1);
    k_out<<<NN, 256, 0, stream>>>(S,  rmax, rsumi, Vl,  nullptr, x_right, x_left,  out_left);
    k_out<<<NN, 256, 0, stream>>>(ST, cmax, csumi, Vr0, Vr1,     x_left,  x_right, out_right);
}

// Round 6
// 788.746 us; speedup vs baseline: 4.6433x; 1.1641x over previous
//
#include <hip/hip_runtime.h>
#include <math.h>

// Problem constants
#define BB 4
#define CC 64
#define C2 128
#define HH 128
#define WW 256
#define NN (BB*HH)          // 512 row-pairs
#define EPSBN 1e-5f

typedef _Float16 f16;
typedef _Float16 half8 __attribute__((ext_vector_type(8)));
typedef float f32x4 __attribute__((ext_vector_type(4)));

// ---------------------------------------------------------------------------
// K1: fused 1x1 conv (64->64) + concat + batchnorm -> u (channel-last f16)
// via MFMA 16x16x32 f16.  u[n][px][128].  grid 512 = (b,h); 256 thr = 4 waves.
// ---------------------------------------------------------------------------
__global__ __launch_bounds__(256) void k_catbn_m(
    const float* __restrict__ x, const float* __restrict__ cw, const float* __restrict__ cb,
    const float* __restrict__ g, const float* __restrict__ bb_, const float* __restrict__ m,
    const float* __restrict__ v, f16* __restrict__ u)
{
    __shared__ f16 Xl[256][72];   // [px][ic]
    __shared__ f16 Wl[64][72];    // [oc][ic]
    __shared__ float sS[64], sT[64], sS2[64], sT2[64];
    int n = blockIdx.x; int b = n >> 7; int h = n & 127; int t = threadIdx.x;
    for (int p = t; p < 2048; p += 256) {
        int idx = p * 2; int o = idx >> 6, i = idx & 63;
        union { f16 h[2]; unsigned int u1; } pr;
        pr.h[0] = (f16)cw[idx]; pr.h[1] = (f16)cw[idx + 1];
        *(unsigned int*)&Wl[o][i] = pr.u1;
    }
    if (t < 64) {
        float inv = rsqrtf(v[t] + EPSBN); float s = g[t] * inv;
        sS[t] = s; sT[t] = bb_[t] + s * (cb[t] - m[t]);
        float inv2 = rsqrtf(v[t + 64] + EPSBN); float s2 = g[t + 64] * inv2;
        sS2[t] = s2; sT2[t] = bb_[t + 64] - s2 * m[t + 64];
    }
    __syncthreads();
    f16* up = u + ((size_t)(n*256 + t)) * 128;
    for (int c8 = 0; c8 < 8; ++c8) {
        float xv8[8];
#pragma unroll
        for (int j = 0; j < 8; ++j)
            xv8[j] = x[(((b*64 + c8*8 + j)*128 + h) << 8) + t];
        union { f16 h[8]; uint4 v4; } pk;
#pragma unroll
        for (int j = 0; j < 8; ++j) {
            int c = c8*8 + j;
            pk.h[j] = (f16)(sS2[c]*xv8[j] + sT2[c]);
        }
        *(uint4*)(up + 64 + c8*8) = pk.v4;
#pragma unroll
        for (int j2 = 0; j2 < 4; ++j2) {
            union { f16 h[2]; unsigned int u1; } q;
            q.h[0] = (f16)xv8[j2*2]; q.h[1] = (f16)xv8[j2*2 + 1];
            *(unsigned int*)&Xl[t][c8*8 + j2*2] = q.u1;
        }
    }
    __syncthreads();
    int lane = t & 63, wv = t >> 6;
    int m16 = lane & 15, quad = lane >> 4;
    half8 af[4][2], bf[4][2];
#pragma unroll
    for (int mt = 0; mt < 4; ++mt)
#pragma unroll
        for (int kk = 0; kk < 2; ++kk)
            af[mt][kk] = *(const half8*)&Wl[mt*16 + m16][kk*32 + quad*8];
#pragma unroll
    for (int nt = 0; nt < 4; ++nt)
#pragma unroll
        for (int kk = 0; kk < 2; ++kk)
            bf[nt][kk] = *(const half8*)&Xl[wv*64 + nt*16 + m16][kk*32 + quad*8];
    f32x4 acc[4][4] = {};
#pragma unroll
    for (int mt = 0; mt < 4; ++mt)
#pragma unroll
        for (int nt = 0; nt < 4; ++nt) {
            acc[mt][nt] = __builtin_amdgcn_mfma_f32_16x16x32_f16(af[mt][0], bf[nt][0], acc[mt][nt], 0, 0, 0);
            acc[mt][nt] = __builtin_amdgcn_mfma_f32_16x16x32_f16(af[mt][1], bf[nt][1], acc[mt][nt], 0, 0, 0);
        }
#pragma unroll
    for (int mt = 0; mt < 4; ++mt) {
        int ocb = mt*16 + quad*4;
        float s4[4], t4[4];
        *(float4*)s4 = *(const float4*)&sS[ocb];
        *(float4*)t4 = *(const float4*)&sT[ocb];
#pragma unroll
        for (int nt = 0; nt < 4; ++nt) {
            int px = wv*64 + nt*16 + m16;
            union { f16 h[4]; uint2 u2; } ov;
#pragma unroll
            for (int r = 0; r < 4; ++r)
                ov.h[r] = (f16)(s4[r]*acc[mt][nt][r] + t4[r]);
            *(uint2*)(u + ((size_t)(n*256 + px))*128 + ocb) = ov.u2;
        }
    }
}

// ---------------------------------------------------------------------------
// K2/K3: grouped 3x3 conv via implicit-GEMM f16 MFMA 16x16x32.
// ---------------------------------------------------------------------------
template<bool LEAKY, bool RES>
__global__ __launch_bounds__(256) void k_conv3m(
    const f16* __restrict__ in, const float* __restrict__ wgt,
    const float* __restrict__ bias, const f16* __restrict__ res,
    f16* __restrict__ out)
{
    __shared__ f16 Wl[32*296];    // [mo][k] stride 296
    __shared__ f16 Xl[3*130*40];  // [row][px][ic] px-stride 40
    int n = blockIdx.x; int b = n >> 7; int h = n & 127;
    int g = blockIdx.y; int w0 = blockIdx.z * 128;
    int t = threadIdx.x;
    for (int p = t; p < 4608; p += 256) {
        int kidx = p * 2;
        int mo = kidx / 288; int kr = kidx - mo*288;
        int ic = kr & 31; int ks = kr >> 5;
        int gb = ((g*32 + mo)*32 + ic)*9 + ks;
        union { f16 h[2]; unsigned int u; } pr;
        pr.h[0] = (f16)wgt[gb];
        pr.h[1] = (f16)wgt[gb + 9];
        *(unsigned int*)&Wl[mo*296 + kr] = pr.u;
    }
    for (int idx = t; idx < 1560; idx += 256) {
        int r = idx / 520; int rem = idx - r*520; int p = rem >> 2; int q = rem & 3;
        int hr = h + r - 1; int wg = w0 + p - 1;
        uint4 val = make_uint4(0,0,0,0);
        if (p < 130 && (unsigned)wg < 256u && (unsigned)hr < 128u)
            val = *(const uint4*)(in + ((size_t)((b*128 + hr)*256 + wg))*128 + g*32 + q*8);
        if (p < 130)
            *(uint4*)&Xl[(r*130 + p)*40 + q*8] = val;
    }
    __syncthreads();
    int lane = t & 63, wv = t >> 6;
    int m16 = lane & 15, quad = lane >> 4;
    f32x4 acc[2][2] = {};
#pragma unroll
    for (int ks = 0; ks < 9; ++ks) {
        int ky = ks / 3, kx = ks - ky*3;
        half8 af0 = *(const half8*)&Wl[m16*296 + ks*32 + quad*8];
        half8 af1 = *(const half8*)&Wl[(16 + m16)*296 + ks*32 + quad*8];
        int px0 = wv*32 + m16;
        half8 bf0 = *(const half8*)&Xl[(ky*130 + px0 + kx)*40 + quad*8];
        half8 bf1 = *(const half8*)&Xl[(ky*130 + px0 + 16 + kx)*40 + quad*8];
        acc[0][0] = __builtin_amdgcn_mfma_f32_16x16x32_f16(af0, bf0, acc[0][0], 0, 0, 0);
        acc[0][1] = __builtin_amdgcn_mfma_f32_16x16x32_f16(af0, bf1, acc[0][1], 0, 0, 0);
        acc[1][0] = __builtin_amdgcn_mfma_f32_16x16x32_f16(af1, bf0, acc[1][0], 0, 0, 0);
        acc[1][1] = __builtin_amdgcn_mfma_f32_16x16x32_f16(af1, bf1, acc[1][1], 0, 0, 0);
    }
    float bo[2][4];
#pragma unroll
    for (int mt = 0; mt < 2; ++mt)
#pragma unroll
        for (int r = 0; r < 4; ++r)
            bo[mt][r] = bias[g*32 + mt*16 + quad*4 + r];
#pragma unroll
    for (int mt = 0; mt < 2; ++mt)
#pragma unroll
        for (int nt = 0; nt < 2; ++nt) {
            int px = w0 + wv*32 + nt*16 + m16;
            int oc = g*32 + mt*16 + quad*4;
            size_t off = ((size_t)((b*128 + h)*256 + px))*128 + oc;
            float rv4[4] = {0.f, 0.f, 0.f, 0.f};
            if (RES) {
                union { f16 h[4]; uint2 v2; } rr;
                rr.v2 = *(const uint2*)(res + off);
#pragma unroll
                for (int r = 0; r < 4; ++r) rv4[r] = (float)rr.h[r];
            }
            union { f16 h[4]; uint2 v2; } ov;
#pragma unroll
            for (int r = 0; r < 4; ++r) {
                float y = acc[mt][nt][r] + bo[mt][r];
                if (LEAKY) y = y > 0.f ? y : 0.1f*y;
                if (RES) y += rv4[r];
                ov.h[r] = (f16)y;
            }
            *(uint2*)(out + off) = ov.v2;
        }
}

// ---------------------------------------------------------------------------
// K4: grouped 1x1 conv (128->64, groups=2) + row-mean subtraction fused.
// ---------------------------------------------------------------------------
__global__ __launch_bounds__(256) void k_conv1x1m(
    const f16* __restrict__ in, const float* __restrict__ wgt,
    f16* __restrict__ outq)
{
    __shared__ float Wl[32][68];
    __shared__ float Ab[32][260];
    __shared__ float meanS[32];
    int n = blockIdx.x; int g = blockIdx.y; int t = threadIdx.x;
    int lane = t & 63, wv = t >> 6;
    for (int idx = t; idx < 2048; idx += 256) Wl[idx >> 6][idx & 63] = wgt[g*2048 + idx];
    float rv[64];
    const f16* rp = in + ((size_t)n*256 + t)*128 + g*64;
#pragma unroll
    for (int i8 = 0; i8 < 8; ++i8) {
        union { uint4 v4; f16 h[8]; } ld;
        ld.v4 = *(const uint4*)(rp + i8*8);
#pragma unroll
        for (int j = 0; j < 8; ++j) rv[i8*8 + j] = (float)ld.h[j];
    }
    __syncthreads();
    float acc[32];
#pragma unroll
    for (int ol = 0; ol < 32; ++ol) {
        float a = 0.f;
#pragma unroll
        for (int i4 = 0; i4 < 16; ++i4) {
            float4 w4 = *(const float4*)&Wl[ol][i4*4];
            a = fmaf(w4.x, rv[i4*4+0], a);
            a = fmaf(w4.y, rv[i4*4+1], a);
            a = fmaf(w4.z, rv[i4*4+2], a);
            a = fmaf(w4.w, rv[i4*4+3], a);
        }
        acc[ol] = a;
        Ab[ol][t] = a;
    }
    __syncthreads();
#pragma unroll
    for (int k = 0; k < 8; ++k) {
        int o = wv*8 + k;
        float s = Ab[o][lane] + Ab[o][lane+64] + Ab[o][lane+128] + Ab[o][lane+192];
#pragma unroll
        for (int off = 32; off; off >>= 1) s += __shfl_xor(s, off);
        if (lane == 0) meanS[o] = s * (1.0f/256.0f);
    }
    __syncthreads();
    f16* qp = outq + ((size_t)n*256 + t)*64 + g*32;
#pragma unroll
    for (int o8 = 0; o8 < 4; ++o8) {
        union { uint4 v4; f16 h[8]; } pk;
#pragma unroll
        for (int e = 0; e < 8; ++e)
            pk.h[e] = (f16)(acc[o8*8+e] - meanS[o8*8+e]);
        *(uint4*)(qp + o8*8) = pk.v4;
    }
}

// ---------------------------------------------------------------------------
// K5: score S = Q K^T per n via MFMA f16.  Writes S and ST (f16).
// ---------------------------------------------------------------------------
__global__ __launch_bounds__(256) void k_score(
    const f16* __restrict__ Q, const f16* __restrict__ K,
    f16* __restrict__ S, f16* __restrict__ ST)
{
    __shared__ f16 Qs[256][72];
    __shared__ f16 Ks[64][72];
    int n = blockIdx.x; int t = threadIdx.x;
    const f16* qg = Q + (size_t)n*16384 + (size_t)t*64;
#pragma unroll
    for (int k = 0; k < 8; ++k)
        *(uint4*)&Qs[t][k*8] = *(const uint4*)(qg + k*8);
    int lane = t & 63, wv = t >> 6;
    int m16 = lane & 15, quad = lane >> 4;
    int m0 = wv*64;
    half8 af[4][2];
    bool afl = false;
    f16* Sn = S + (size_t)n*65536;
    f16* STn = ST + (size_t)n*65536;
    for (int jc = 0; jc < 256; jc += 64) {
        __syncthreads();
        {
            int jj = t >> 2, seg = (t & 3) * 16;
            const f16* kg = K + (size_t)n*16384 + (size_t)(jc + jj)*64 + seg;
            *(uint4*)&Ks[jj][seg]     = *(const uint4*)(kg);
            *(uint4*)&Ks[jj][seg + 8] = *(const uint4*)(kg + 8);
        }
        __syncthreads();
        if (!afl) {
            afl = true;
#pragma unroll
            for (int mt = 0; mt < 4; ++mt)
#pragma unroll
                for (int kk = 0; kk < 2; ++kk)
                    af[mt][kk] = *(const half8*)&Qs[m0 + mt*16 + m16][kk*32 + quad*8];
        }
        half8 bf[4][2];
#pragma unroll
        for (int nt = 0; nt < 4; ++nt)
#pragma unroll
            for (int kk = 0; kk < 2; ++kk)
                bf[nt][kk] = *(const half8*)&Ks[nt*16 + m16][kk*32 + quad*8];
        f32x4 acc[4][4] = {};
#pragma unroll
        for (int mt = 0; mt < 4; ++mt)
#pragma unroll
            for (int nt = 0; nt < 4; ++nt) {
                acc[mt][nt] = __builtin_amdgcn_mfma_f32_16x16x32_f16(af[mt][0], bf[nt][0], acc[mt][nt], 0, 0, 0);
                acc[mt][nt] = __builtin_amdgcn_mfma_f32_16x16x32_f16(af[mt][1], bf[nt][1], acc[mt][nt], 0, 0, 0);
            }
#pragma unroll
        for (int mt = 0; mt < 4; ++mt)
#pragma unroll
            for (int nt = 0; nt < 4; ++nt) {
                int i = m0 + mt*16 + quad*4;
                int j = jc + nt*16 + m16;
                union { f16 h[4]; uint2 u2; } pv;
#pragma unroll
                for (int r = 0; r < 4; ++r) {
                    f16 vv = (f16)acc[mt][nt][r];
                    Sn[(size_t)(i + r)*256 + j] = vv;
                    pv.h[r] = vv;
                }
                *(uint2*)&STn[(size_t)j*256 + i] = pv.u2;
            }
    }
}

// ---------------------------------------------------------------------------
// K6: softmax stats, vectorized tile reads.  grid 512 (one block per n).
// Thread t: rows g*8 + (t>>5), cols (t&31)*8 .. +7 (uint4 loads, coalesced).
// Row stats exact via half-wave shuffles; col stats online + LDS merge.
// ---------------------------------------------------------------------------
__global__ __launch_bounds__(256) void k_stats(
    const f16* __restrict__ S, float* __restrict__ rmax, float* __restrict__ rsumi,
    float* __restrict__ cmax, float* __restrict__ csumi)
{
    __shared__ float CM[8][260], CS[8][260];
    int n = blockIdx.x, t = threadIdx.x;
    int rphase = t >> 5;          // 0..7
    int c0 = (t & 31) * 8;
    const f16* Sp = S + (size_t)n*65536;
    float colm[8], cols[8];
#pragma unroll
    for (int e = 0; e < 8; ++e) { colm[e] = -1e30f; cols[e] = 0.f; }
    for (int g = 0; g < 32; ++g) {
        int row = g*8 + rphase;
        union { uint4 v4; f16 h[8]; } ld;
        ld.v4 = *(const uint4*)(Sp + (size_t)row*256 + c0);
        float v[8];
#pragma unroll
        for (int e = 0; e < 8; ++e) v[e] = (float)ld.h[e];
        float mx = v[0];
#pragma unroll
        for (int e = 1; e < 8; ++e) mx = fmaxf(mx, v[e]);
#pragma unroll
        for (int off = 1; off < 32; off <<= 1) mx = fmaxf(mx, __shfl_xor(mx, off));
        float es = 0.f;
#pragma unroll
        for (int e = 0; e < 8; ++e) es += __expf(v[e] - mx);
#pragma unroll
        for (int off = 1; off < 32; off <<= 1) es += __shfl_xor(es, off);
        if ((t & 31) == 0) { rmax[n*256 + row] = mx; rsumi[n*256 + row] = 1.0f/es; }
#pragma unroll
        for (int e = 0; e < 8; ++e) {
            float nm = fmaxf(colm[e], v[e]);
            cols[e] = cols[e]*__expf(colm[e] - nm) + __expf(v[e] - nm);
            colm[e] = nm;
        }
    }
#pragma unroll
    for (int e = 0; e < 8; ++e) { CM[rphase][c0 + e] = colm[e]; CS[rphase][c0 + e] = cols[e]; }
    __syncthreads();
    float m = CM[0][t], s = CS[0][t];
#pragma unroll
    for (int gp = 1; gp < 8; ++gp) {
        float m2 = CM[gp][t], s2 = CS[gp][t];
        float nm = fmaxf(m, m2);
        s = s*__expf(m - nm) + s2*__expf(m2 - nm);
        m = nm;
    }
    cmax[n*256 + t] = m;
    csumi[n*256 + t] = 1.0f/s;
}

// ---------------------------------------------------------------------------
// K8: out = xP*(1-tv) + (P @ xB)*tv,  tv = tanh(5 V), V fused in-kernel.
// P rows from P16 (S for left / ST for right), norm (sm,si) per row.
// V[t] = sum_j (sum_d P[t+d][j]) * exp(raw[t][j]-om[j])*oi[j]  (other norm).
// grid 512 n; 256 thr.
// ---------------------------------------------------------------------------
__global__ __launch_bounds__(256) void k_out(
    const f16* __restrict__ P16, const float* __restrict__ sm, const float* __restrict__ si,
    const float* __restrict__ om, const float* __restrict__ oi,
    const float* __restrict__ xB, const float* __restrict__ xP,
    float* __restrict__ outp)
{
    __shared__ f16 Pl[260][72];   // rows offset +2; rows 0,1,258,259 stay zero
    __shared__ f16 Xl[64][72];
    __shared__ float cmS[256], ciS[256];
    __shared__ float Vs[256];
    int n = blockIdx.x; int b = n >> 7; int h = n & 127;
    int t = threadIdx.x;
    int lane = t & 63, wv = t >> 6;
    int m16 = lane & 15, quad = lane >> 4;
    // zero pad rows (rows 0-1 and 258-259 are contiguous spans of 144 f16)
    if (t < 18)      *(uint4*)(&Pl[0][0]   + t*8)      = make_uint4(0,0,0,0);
    else if (t < 36) *(uint4*)(&Pl[258][0] + (t-18)*8) = make_uint4(0,0,0,0);
    cmS[t] = om[n*256 + t];
    ciS[t] = oi[n*256 + t];
    float rm = sm[n*256 + t], ri = si[n*256 + t];
    f32x4 acc[4][4] = {};
    float vacc = 0.f;
    for (int kc = 0; kc < 256; kc += 64) {
        uint4 raw8[8];
        const f16* pg = P16 + (size_t)n*65536 + (size_t)t*256 + kc;
#pragma unroll
        for (int k8 = 0; k8 < 8; ++k8) {
            union { uint4 v4; f16 h[8]; } ldu, stu;
            ldu.v4 = *(const uint4*)(pg + k8*8);
            raw8[k8] = ldu.v4;
#pragma unroll
            for (int e = 0; e < 8; ++e)
                stu.h[e] = (f16)(__expf((float)ldu.h[e] - rm) * ri);
            *(uint4*)&Pl[t + 2][k8*8] = stu.v4;
        }
        {
            int c = t >> 2, j0 = (t & 3) * 16;
            const float* xg = xB + (((size_t)(b*64 + c)*128 + h) << 8) + kc + j0;
            union { uint4 v4; f16 h[8]; } xu0, xu1;
#pragma unroll
            for (int e = 0; e < 8; ++e) xu0.h[e] = (f16)xg[e];
#pragma unroll
            for (int e = 0; e < 8; ++e) xu1.h[e] = (f16)xg[8 + e];
            *(uint4*)&Xl[c][j0]     = xu0.v4;
            *(uint4*)&Xl[c][j0 + 8] = xu1.v4;
        }
        __syncthreads();
        // ---- MFMA P @ xB ----
        int mbase = wv*64;
        half8 a0[4][2], b0[4][2];
#pragma unroll
        for (int mt = 0; mt < 4; ++mt)
#pragma unroll
            for (int kk = 0; kk < 2; ++kk)
                a0[mt][kk] = *(const half8*)&Pl[mbase + mt*16 + m16 + 2][kk*32 + quad*8];
#pragma unroll
        for (int nt = 0; nt < 4; ++nt)
#pragma unroll
            for (int kk = 0; kk < 2; ++kk)
                b0[nt][kk] = *(const half8*)&Xl[nt*16 + m16][kk*32 + quad*8];
#pragma unroll
        for (int mt = 0; mt < 4; ++mt)
#pragma unroll
            for (int nt = 0; nt < 4; ++nt) {
                acc[mt][nt] = __builtin_amdgcn_mfma_f32_16x16x32_f16(a0[mt][0], b0[nt][0], acc[mt][nt], 0, 0, 0);
                acc[mt][nt] = __builtin_amdgcn_mfma_f32_16x16x32_f16(a0[mt][1], b0[nt][1], acc[mt][nt], 0, 0, 0);
            }
        // ---- fused V accumulation: vertical window from LDS + other-norm exp ----
#pragma unroll
        for (int j8 = 0; j8 < 8; ++j8) {
            int jl = j8*8;
            half8 w0 = *(const half8*)&Pl[t + 0][jl];
            half8 w1 = *(const half8*)&Pl[t + 1][jl];
            half8 w2 = *(const half8*)&Pl[t + 2][jl];
            half8 w3 = *(const half8*)&Pl[t + 3][jl];
            half8 w4 = *(const half8*)&Pl[t + 4][jl];
            half8 win = w0 + w1 + w2 + w3 + w4;
            union { uint4 v4; f16 h[8]; } rw; rw.v4 = raw8[j8];
#pragma unroll
            for (int e = 0; e < 8; ++e) {
                int j = kc + jl + e;
                float Bv = __expf((float)rw.h[e] - cmS[j]) * ciS[j];
                vacc = fmaf((float)win[e], Bv, vacc);
            }
        }
        __syncthreads();
    }
    Vs[t] = vacc;
    __syncthreads();
#pragma unroll
    for (int mt = 0; mt < 4; ++mt) {
        int i0 = wv*64 + mt*16 + quad*4;
        float v4[4];
        *(float4*)v4 = *(const float4*)&Vs[i0];
        float tv[4];
#pragma unroll
        for (int r = 0; r < 4; ++r) tv[r] = tanhf(5.f*v4[r]);
#pragma unroll
        for (int nt = 0; nt < 4; ++nt) {
            int c = nt*16 + m16;
            size_t base = (((size_t)(b*64 + c)*128 + h) << 8) + i0;
            float xp4[4]; *(float4*)xp4 = *(const float4*)&xP[base];
            float o4[4];
#pragma unroll
            for (int r = 0; r < 4; ++r)
                o4[r] = xp4[r]*(1.f - tv[r]) + acc[mt][nt][r]*tv[r];
            *(float4*)&outp[base] = *(float4*)o4;
        }
    }
}

// ---------------------------------------------------------------------------
extern "C" void kernel_launch(void* const* d_in, const int* in_sizes, int n_in,
                              void* d_out, int out_size, void* d_ws, size_t ws_size,
                              hipStream_t stream)
{
    const float* x_left  = (const float*)d_in[0];
    const float* x_right = (const float*)d_in[1];
    const float* conv1_w = (const float*)d_in[2];
    const float* conv1_b = (const float*)d_in[3];
    const float* conv2_w = (const float*)d_in[4];
    const float* conv2_b = (const float*)d_in[5];
    const float* bn_g    = (const float*)d_in[6];
    const float* bn_b    = (const float*)d_in[7];
    const float* bn_m    = (const float*)d_in[8];
    const float* bn_v    = (const float*)d_in[9];
    const float* rb_w1   = (const float*)d_in[10];
    const float* rb_b1   = (const float*)d_in[11];
    const float* rb_w2   = (const float*)d_in[12];
    const float* rb_b2   = (const float*)d_in[13];
    const float* bq_w    = (const float*)d_in[14];
    const float* bs_w    = (const float*)d_in[16];

    f16* W16 = (f16*)d_ws;
    f16* u  = W16;                       // 16,777,216 els
    f16* y1 = W16 + 16777216;            // 16,777,216
    f16* r  = W16 + 33554432;            // 16,777,216
    f16* S  = W16;                       // 33,554,432 (aliases u+y1)
    f16* ST = W16 + 33554432;            // 33,554,432 (aliases r + fresh)
    f16* Qh = W16 + 67108864;            //  8,388,608
    f16* Kh = W16 + 75497472;            //  8,388,608
    float* F32  = (float*)(W16 + 83886080);
    float* rmax  = F32;                  // 131,072
    float* rsumi = F32 + 131072;
    float* cmax  = F32 + 262144;         // 131,072
    float* csumi = F32 + 393216;         // 131,072

    float* out_left  = (float*)d_out;
    float* out_right = (float*)d_out + 8388608;

    // ---- left branch -> Q ----
    k_catbn_m<<<NN, 256, 0, stream>>>(x_left, conv1_w, conv1_b, bn_g, bn_b, bn_m, bn_v, u);
    k_conv3m<true,  false><<<dim3(NN, 4, 2), 256, 0, stream>>>(u, rb_w1, rb_b1, nullptr, y1);
    k_conv3m<false, true ><<<dim3(NN, 4, 2), 256, 0, stream>>>(y1, rb_w2, rb_b2, u, r);
    k_conv1x1m<<<dim3(NN, 2), 256, 0, stream>>>(r, bq_w, Qh);

    // ---- right branch -> K ----
    k_catbn_m<<<NN, 256, 0, stream>>>(x_right, conv2_w, conv2_b, bn_g, bn_b, bn_m, bn_v, u);
    k_conv3m<true,  false><<<dim3(NN, 4, 2), 256, 0, stream>>>(u, rb_w1, rb_b1, nullptr, y1);
    k_conv3m<false, true ><<<dim3(NN, 4, 2), 256, 0, stream>>>(y1, rb_w2, rb_b2, u, r);
    k_conv1x1m<<<dim3(NN, 2), 256, 0, stream>>>(r, bs_w, Kh);

    // ---- attention ----
    k_score<<<NN, 256, 0, stream>>>(Qh, Kh, S, ST);
    k_stats<<<NN, 256, 0, stream>>>(S, rmax, rsumi, cmax, csumi);
    // left: P = softmax_rows(S) (rmax/rsumi); V_l uses col norm (cmax/csumi)
    k_out<<<NN, 256, 0, stream>>>(S,  rmax, rsumi, cmax, csumi, x_right, x_left,  out_left);
    // right: P = softmax_rows(ST) (cmax/csumi); V_r uses row norm (rmax/rsumi)
    k_out<<<NN, 256, 0, stream>>>(ST, cmax, csumi, rmax, rsumi, x_left,  x_right, out_right);
}

// Round 7
// 606.979 us; speedup vs baseline: 6.0338x; 1.2995x over previous
//
#include <hip/hip_runtime.h>
#include <math.h>

// Problem constants
#define BB 4
#define CC 64
#define C2 128
#define HH 128
#define WW 256
#define NN (BB*HH)          // 512 row-pairs
#define EPSBN 1e-5f

typedef _Float16 f16;
typedef _Float16 half8 __attribute__((ext_vector_type(8)));
typedef float f32x4 __attribute__((ext_vector_type(4)));

// ---------------------------------------------------------------------------
// K0: weight prep — rb_w fp32 [o][icg][3][3] -> f16 [g][mo][ks*32+ic]
// (MFMA-fragment order; conv blocks then read coalesced b128).  grid (4,2).
// ---------------------------------------------------------------------------
__global__ __launch_bounds__(256) void k_wprep(
    const float* __restrict__ w1, const float* __restrict__ w2,
    f16* __restrict__ wp1, f16* __restrict__ wp2)
{
    int g = blockIdx.x; int which = blockIdx.y;
    const float* src = which ? w2 : w1;
    f16* dst = which ? wp2 : wp1;
    for (int p = threadIdx.x; p < 9216; p += 256) {
        int mo = p / 288; int kr = p - mo*288;
        int ks = kr >> 5; int ic = kr & 31;
        dst[g*9216 + p] = (f16)src[((g*32 + mo)*32 + ic)*9 + ks];
    }
}

// ---------------------------------------------------------------------------
// K1: fused 1x1 conv (64->64) + concat + batchnorm -> u (channel-last f16)
// via MFMA 16x16x32 f16.  u[n][px][128].  grid 512 = (b,h); 256 thr = 4 waves.
// ---------------------------------------------------------------------------
__global__ __launch_bounds__(256) void k_catbn_m(
    const float* __restrict__ x, const float* __restrict__ cw, const float* __restrict__ cb,
    const float* __restrict__ g, const float* __restrict__ bb_, const float* __restrict__ m,
    const float* __restrict__ v, f16* __restrict__ u)
{
    __shared__ f16 Xl[256][72];   // [px][ic]
    __shared__ f16 Wl[64][72];    // [oc][ic]
    __shared__ float sS[64], sT[64], sS2[64], sT2[64];
    int n = blockIdx.x; int b = n >> 7; int h = n & 127; int t = threadIdx.x;
    for (int p = t; p < 2048; p += 256) {
        int idx = p * 2; int o = idx >> 6, i = idx & 63;
        union { f16 h[2]; unsigned int u1; } pr;
        pr.h[0] = (f16)cw[idx]; pr.h[1] = (f16)cw[idx + 1];
        *(unsigned int*)&Wl[o][i] = pr.u1;
    }
    if (t < 64) {
        float inv = rsqrtf(v[t] + EPSBN); float s = g[t] * inv;
        sS[t] = s; sT[t] = bb_[t] + s * (cb[t] - m[t]);
        float inv2 = rsqrtf(v[t + 64] + EPSBN); float s2 = g[t + 64] * inv2;
        sS2[t] = s2; sT2[t] = bb_[t + 64] - s2 * m[t + 64];
    }
    __syncthreads();
    f16* up = u + ((size_t)(n*256 + t)) * 128;
    for (int c8 = 0; c8 < 8; ++c8) {
        float xv8[8];
#pragma unroll
        for (int j = 0; j < 8; ++j)
            xv8[j] = x[(((b*64 + c8*8 + j)*128 + h) << 8) + t];
        union { f16 h[8]; uint4 v4; } pk;
#pragma unroll
        for (int j = 0; j < 8; ++j) {
            int c = c8*8 + j;
            pk.h[j] = (f16)(sS2[c]*xv8[j] + sT2[c]);
        }
        *(uint4*)(up + 64 + c8*8) = pk.v4;
#pragma unroll
        for (int j2 = 0; j2 < 4; ++j2) {
            union { f16 h[2]; unsigned int u1; } q;
            q.h[0] = (f16)xv8[j2*2]; q.h[1] = (f16)xv8[j2*2 + 1];
            *(unsigned int*)&Xl[t][c8*8 + j2*2] = q.u1;
        }
    }
    __syncthreads();
    int lane = t & 63, wv = t >> 6;
    int m16 = lane & 15, quad = lane >> 4;
    half8 af[4][2], bf[4][2];
#pragma unroll
    for (int mt = 0; mt < 4; ++mt)
#pragma unroll
        for (int kk = 0; kk < 2; ++kk)
            af[mt][kk] = *(const half8*)&Wl[mt*16 + m16][kk*32 + quad*8];
#pragma unroll
    for (int nt = 0; nt < 4; ++nt)
#pragma unroll
        for (int kk = 0; kk < 2; ++kk)
            bf[nt][kk] = *(const half8*)&Xl[wv*64 + nt*16 + m16][kk*32 + quad*8];
    f32x4 acc[4][4] = {};
#pragma unroll
    for (int mt = 0; mt < 4; ++mt)
#pragma unroll
        for (int nt = 0; nt < 4; ++nt) {
            acc[mt][nt] = __builtin_amdgcn_mfma_f32_16x16x32_f16(af[mt][0], bf[nt][0], acc[mt][nt], 0, 0, 0);
            acc[mt][nt] = __builtin_amdgcn_mfma_f32_16x16x32_f16(af[mt][1], bf[nt][1], acc[mt][nt], 0, 0, 0);
        }
#pragma unroll
    for (int mt = 0; mt < 4; ++mt) {
        int ocb = mt*16 + quad*4;
        float s4[4], t4[4];
        *(float4*)s4 = *(const float4*)&sS[ocb];
        *(float4*)t4 = *(const float4*)&sT[ocb];
#pragma unroll
        for (int nt = 0; nt < 4; ++nt) {
            int px = wv*64 + nt*16 + m16;
            union { f16 h[4]; uint2 u2; } ov;
#pragma unroll
            for (int r = 0; r < 4; ++r)
                ov.h[r] = (f16)(s4[r]*acc[mt][nt][r] + t4[r]);
            *(uint2*)(u + ((size_t)(n*256 + px))*128 + ocb) = ov.u2;
        }
    }
}

// ---------------------------------------------------------------------------
// K2/K3: grouped 3x3 conv, implicit-GEMM f16 MFMA, 4 output rows per block.
// Weights pre-transformed (k_wprep) -> loaded straight into registers.
// grid (128 = b*htile, 4 group, 2 wtile); 256 thr = 4 waves.
// Wave: 32 px x 32 oc per row, 4 rows.  LDS: 6 input rows only (62.4 KB).
// ---------------------------------------------------------------------------
template<bool LEAKY, bool RES>
__global__ __launch_bounds__(256, 2) void k_conv3r(
    const f16* __restrict__ in, const f16* __restrict__ wp,
    const float* __restrict__ bias, const f16* __restrict__ res,
    f16* __restrict__ out)
{
    __shared__ f16 Xl[6*130*40];  // [row][px][ic] px-stride 40
    int b = blockIdx.x >> 5; int h0 = (blockIdx.x & 31) * 4;
    int g = blockIdx.y; int w0 = blockIdx.z * 128;
    int t = threadIdx.x;
    int lane = t & 63, wv = t >> 6;
    int m16 = lane & 15, quad = lane >> 4;
    // ---- weight fragments into registers (coalesced b128 from prepped) ----
    const f16* wg = wp + g*9216;
    half8 af[2][9];
#pragma unroll
    for (int mt = 0; mt < 2; ++mt)
#pragma unroll
        for (int ks = 0; ks < 9; ++ks)
            af[mt][ks] = *(const half8*)(wg + (mt*16 + m16)*288 + ks*32 + quad*8);
    float bo[2][4];
#pragma unroll
    for (int mt = 0; mt < 2; ++mt)
#pragma unroll
        for (int r = 0; r < 4; ++r)
            bo[mt][r] = bias[g*32 + mt*16 + quad*4 + r];
    // ---- stage 6 input rows (h0-1 .. h0+4) ----
    for (int idx = t; idx < 3120; idx += 256) {
        int r = idx / 520; int rem = idx - r*520; int p = rem >> 2; int q = rem & 3;
        int hr = h0 + r - 1; int wg2 = w0 + p - 1;
        uint4 val = make_uint4(0,0,0,0);
        if ((unsigned)wg2 < 256u && (unsigned)hr < 128u)
            val = *(const uint4*)(in + ((size_t)((b*128 + hr)*256 + wg2))*128 + g*32 + q*8);
        *(uint4*)&Xl[(r*130 + p)*40 + q*8] = val;
    }
    __syncthreads();
    int px0 = wv*32 + m16;
#pragma unroll
    for (int rr = 0; rr < 4; ++rr) {
        f32x4 acc[2][2] = {};
#pragma unroll
        for (int ks = 0; ks < 9; ++ks) {
            int ky = ks / 3, kx = ks - ky*3;
            half8 bf0 = *(const half8*)&Xl[((rr + ky)*130 + px0 + kx)*40 + quad*8];
            half8 bf1 = *(const half8*)&Xl[((rr + ky)*130 + px0 + 16 + kx)*40 + quad*8];
            acc[0][0] = __builtin_amdgcn_mfma_f32_16x16x32_f16(af[0][ks], bf0, acc[0][0], 0, 0, 0);
            acc[0][1] = __builtin_amdgcn_mfma_f32_16x16x32_f16(af[0][ks], bf1, acc[0][1], 0, 0, 0);
            acc[1][0] = __builtin_amdgcn_mfma_f32_16x16x32_f16(af[1][ks], bf0, acc[1][0], 0, 0, 0);
            acc[1][1] = __builtin_amdgcn_mfma_f32_16x16x32_f16(af[1][ks], bf1, acc[1][1], 0, 0, 0);
        }
        int h = h0 + rr;
#pragma unroll
        for (int mt = 0; mt < 2; ++mt)
#pragma unroll
            for (int nt = 0; nt < 2; ++nt) {
                int px = w0 + wv*32 + nt*16 + m16;
                int oc = g*32 + mt*16 + quad*4;
                size_t off = ((size_t)((b*128 + h)*256 + px))*128 + oc;
                float rv4[4] = {0.f, 0.f, 0.f, 0.f};
                if (RES) {
                    union { f16 h[4]; uint2 v2; } rrd;
                    rrd.v2 = *(const uint2*)(res + off);
#pragma unroll
                    for (int r = 0; r < 4; ++r) rv4[r] = (float)rrd.h[r];
                }
                union { f16 h[4]; uint2 v2; } ov;
#pragma unroll
                for (int r = 0; r < 4; ++r) {
                    float y = acc[mt][nt][r] + bo[mt][r];
                    if (LEAKY) y = y > 0.f ? y : 0.1f*y;
                    if (RES) y += rv4[r];
                    ov.h[r] = (f16)y;
                }
                *(uint2*)(out + off) = ov.v2;
            }
    }
}

// ---------------------------------------------------------------------------
// K4: grouped 1x1 conv (128->64, groups=2) + row-mean subtraction fused.
// ---------------------------------------------------------------------------
__global__ __launch_bounds__(256) void k_conv1x1m(
    const f16* __restrict__ in, const float* __restrict__ wgt,
    f16* __restrict__ outq)
{
    __shared__ float Wl[32][68];
    __shared__ float Ab[32][260];
    __shared__ float meanS[32];
    int n = blockIdx.x; int g = blockIdx.y; int t = threadIdx.x;
    int lane = t & 63, wv = t >> 6;
    for (int idx = t; idx < 2048; idx += 256) Wl[idx >> 6][idx & 63] = wgt[g*2048 + idx];
    float rv[64];
    const f16* rp = in + ((size_t)n*256 + t)*128 + g*64;
#pragma unroll
    for (int i8 = 0; i8 < 8; ++i8) {
        union { uint4 v4; f16 h[8]; } ld;
        ld.v4 = *(const uint4*)(rp + i8*8);
#pragma unroll
        for (int j = 0; j < 8; ++j) rv[i8*8 + j] = (float)ld.h[j];
    }
    __syncthreads();
    float acc[32];
#pragma unroll
    for (int ol = 0; ol < 32; ++ol) {
        float a = 0.f;
#pragma unroll
        for (int i4 = 0; i4 < 16; ++i4) {
            float4 w4 = *(const float4*)&Wl[ol][i4*4];
            a = fmaf(w4.x, rv[i4*4+0], a);
            a = fmaf(w4.y, rv[i4*4+1], a);
            a = fmaf(w4.z, rv[i4*4+2], a);
            a = fmaf(w4.w, rv[i4*4+3], a);
        }
        acc[ol] = a;
        Ab[ol][t] = a;
    }
    __syncthreads();
#pragma unroll
    for (int k = 0; k < 8; ++k) {
        int o = wv*8 + k;
        float s = Ab[o][lane] + Ab[o][lane+64] + Ab[o][lane+128] + Ab[o][lane+192];
#pragma unroll
        for (int off = 32; off; off >>= 1) s += __shfl_xor(s, off);
        if (lane == 0) meanS[o] = s * (1.0f/256.0f);
    }
    __syncthreads();
    f16* qp = outq + ((size_t)n*256 + t)*64 + g*32;
#pragma unroll
    for (int o8 = 0; o8 < 4; ++o8) {
        union { uint4 v4; f16 h[8]; } pk;
#pragma unroll
        for (int e = 0; e < 8; ++e)
            pk.h[e] = (f16)(acc[o8*8+e] - meanS[o8*8+e]);
        *(uint4*)(qp + o8*8) = pk.v4;
    }
}

// ---------------------------------------------------------------------------
// K5: score S = Q K^T per n via MFMA f16.  Writes S and ST (f16).
// ---------------------------------------------------------------------------
__global__ __launch_bounds__(256) void k_score(
    const f16* __restrict__ Q, const f16* __restrict__ K,
    f16* __restrict__ S, f16* __restrict__ ST)
{
    __shared__ f16 Qs[256][72];
    __shared__ f16 Ks[64][72];
    int n = blockIdx.x; int t = threadIdx.x;
    const f16* qg = Q + (size_t)n*16384 + (size_t)t*64;
#pragma unroll
    for (int k = 0; k < 8; ++k)
        *(uint4*)&Qs[t][k*8] = *(const uint4*)(qg + k*8);
    int lane = t & 63, wv = t >> 6;
    int m16 = lane & 15, quad = lane >> 4;
    int m0 = wv*64;
    half8 af[4][2];
    bool afl = false;
    f16* Sn = S + (size_t)n*65536;
    f16* STn = ST + (size_t)n*65536;
    for (int jc = 0; jc < 256; jc += 64) {
        __syncthreads();
        {
            int jj = t >> 2, seg = (t & 3) * 16;
            const f16* kg = K + (size_t)n*16384 + (size_t)(jc + jj)*64 + seg;
            *(uint4*)&Ks[jj][seg]     = *(const uint4*)(kg);
            *(uint4*)&Ks[jj][seg + 8] = *(const uint4*)(kg + 8);
        }
        __syncthreads();
        if (!afl) {
            afl = true;
#pragma unroll
            for (int mt = 0; mt < 4; ++mt)
#pragma unroll
                for (int kk = 0; kk < 2; ++kk)
                    af[mt][kk] = *(const half8*)&Qs[m0 + mt*16 + m16][kk*32 + quad*8];
        }
        half8 bf[4][2];
#pragma unroll
        for (int nt = 0; nt < 4; ++nt)
#pragma unroll
            for (int kk = 0; kk < 2; ++kk)
                bf[nt][kk] = *(const half8*)&Ks[nt*16 + m16][kk*32 + quad*8];
        f32x4 acc[4][4] = {};
#pragma unroll
        for (int mt = 0; mt < 4; ++mt)
#pragma unroll
            for (int nt = 0; nt < 4; ++nt) {
                acc[mt][nt] = __builtin_amdgcn_mfma_f32_16x16x32_f16(af[mt][0], bf[nt][0], acc[mt][nt], 0, 0, 0);
                acc[mt][nt] = __builtin_amdgcn_mfma_f32_16x16x32_f16(af[mt][1], bf[nt][1], acc[mt][nt], 0, 0, 0);
            }
#pragma unroll
        for (int mt = 0; mt < 4; ++mt)
#pragma unroll
            for (int nt = 0; nt < 4; ++nt) {
                int i = m0 + mt*16 + quad*4;
                int j = jc + nt*16 + m16;
                union { f16 h[4]; uint2 u2; } pv;
#pragma unroll
                for (int r = 0; r < 4; ++r) {
                    f16 vv = (f16)acc[mt][nt][r];
                    Sn[(size_t)(i + r)*256 + j] = vv;
                    pv.h[r] = vv;
                }
                *(uint2*)&STn[(size_t)j*256 + i] = pv.u2;
            }
    }
}

// ---------------------------------------------------------------------------
// K6: softmax stats, vectorized tile reads.  grid 512 (one block per n).
// ---------------------------------------------------------------------------
__global__ __launch_bounds__(256) void k_stats(
    const f16* __restrict__ S, float* __restrict__ rmax, float* __restrict__ rsumi,
    float* __restrict__ cmax, float* __restrict__ csumi)
{
    __shared__ float CM[8][260], CS[8][260];
    int n = blockIdx.x, t = threadIdx.x;
    int rphase = t >> 5;          // 0..7
    int c0 = (t & 31) * 8;
    const f16* Sp = S + (size_t)n*65536;
    float colm[8], cols[8];
#pragma unroll
    for (int e = 0; e < 8; ++e) { colm[e] = -1e30f; cols[e] = 0.f; }
    for (int g = 0; g < 32; ++g) {
        int row = g*8 + rphase;
        union { uint4 v4; f16 h[8]; } ld;
        ld.v4 = *(const uint4*)(Sp + (size_t)row*256 + c0);
        float v[8];
#pragma unroll
        for (int e = 0; e < 8; ++e) v[e] = (float)ld.h[e];
        float mx = v[0];
#pragma unroll
        for (int e = 1; e < 8; ++e) mx = fmaxf(mx, v[e]);
#pragma unroll
        for (int off = 1; off < 32; off <<= 1) mx = fmaxf(mx, __shfl_xor(mx, off));
        float es = 0.f;
#pragma unroll
        for (int e = 0; e < 8; ++e) es += __expf(v[e] - mx);
#pragma unroll
        for (int off = 1; off < 32; off <<= 1) es += __shfl_xor(es, off);
        if ((t & 31) == 0) { rmax[n*256 + row] = mx; rsumi[n*256 + row] = 1.0f/es; }
#pragma unroll
        for (int e = 0; e < 8; ++e) {
            float nm = fmaxf(colm[e], v[e]);
            cols[e] = cols[e]*__expf(colm[e] - nm) + __expf(v[e] - nm);
            colm[e] = nm;
        }
    }
#pragma unroll
    for (int e = 0; e < 8; ++e) { CM[rphase][c0 + e] = colm[e]; CS[rphase][c0 + e] = cols[e]; }
    __syncthreads();
    float m = CM[0][t], s = CS[0][t];
#pragma unroll
    for (int gp = 1; gp < 8; ++gp) {
        float m2 = CM[gp][t], s2 = CS[gp][t];
        float nm = fmaxf(m, m2);
        s = s*__expf(m - nm) + s2*__expf(m2 - nm);
        m = nm;
    }
    cmax[n*256 + t] = m;
    csumi[n*256 + t] = 1.0f/s;
}

// ---------------------------------------------------------------------------
// K8: out = xP*(1-tv) + (P @ xB)*tv,  tv = tanh(5 V), V fused in-kernel.
// ---------------------------------------------------------------------------
__global__ __launch_bounds__(256) void k_out(
    const f16* __restrict__ P16, const float* __restrict__ sm, const float* __restrict__ si,
    const float* __restrict__ om, const float* __restrict__ oi,
    const float* __restrict__ xB, const float* __restrict__ xP,
    float* __restrict__ outp)
{
    __shared__ f16 Pl[260][72];   // rows offset +2; rows 0,1,258,259 stay zero
    __shared__ f16 Xl[64][72];
    __shared__ float cmS[256], ciS[256];
    __shared__ float Vs[256];
    int n = blockIdx.x; int b = n >> 7; int h = n & 127;
    int t = threadIdx.x;
    int lane = t & 63, wv = t >> 6;
    int m16 = lane & 15, quad = lane >> 4;
    if (t < 18)      *(uint4*)(&Pl[0][0]   + t*8)      = make_uint4(0,0,0,0);
    else if (t < 36) *(uint4*)(&Pl[258][0] + (t-18)*8) = make_uint4(0,0,0,0);
    cmS[t] = om[n*256 + t];
    ciS[t] = oi[n*256 + t];
    float rm = sm[n*256 + t], ri = si[n*256 + t];
    f32x4 acc[4][4] = {};
    float vacc = 0.f;
    for (int kc = 0; kc < 256; kc += 64) {
        uint4 raw8[8];
        const f16* pg = P16 + (size_t)n*65536 + (size_t)t*256 + kc;
#pragma unroll
        for (int k8 = 0; k8 < 8; ++k8) {
            union { uint4 v4; f16 h[8]; } ldu, stu;
            ldu.v4 = *(const uint4*)(pg + k8*8);
            raw8[k8] = ldu.v4;
#pragma unroll
            for (int e = 0; e < 8; ++e)
                stu.h[e] = (f16)(__expf((float)ldu.h[e] - rm) * ri);
            *(uint4*)&Pl[t + 2][k8*8] = stu.v4;
        }
        {
            int c = t >> 2, j0 = (t & 3) * 16;
            const float* xg = xB + (((size_t)(b*64 + c)*128 + h) << 8) + kc + j0;
            union { uint4 v4; f16 h[8]; } xu0, xu1;
#pragma unroll
            for (int e = 0; e < 8; ++e) xu0.h[e] = (f16)xg[e];
#pragma unroll
            for (int e = 0; e < 8; ++e) xu1.h[e] = (f16)xg[8 + e];
            *(uint4*)&Xl[c][j0]     = xu0.v4;
            *(uint4*)&Xl[c][j0 + 8] = xu1.v4;
        }
        __syncthreads();
        int mbase = wv*64;
        half8 a0[4][2], b0[4][2];
#pragma unroll
        for (int mt = 0; mt < 4; ++mt)
#pragma unroll
            for (int kk = 0; kk < 2; ++kk)
                a0[mt][kk] = *(const half8*)&Pl[mbase + mt*16 + m16 + 2][kk*32 + quad*8];
#pragma unroll
        for (int nt = 0; nt < 4; ++nt)
#pragma unroll
            for (int kk = 0; kk < 2; ++kk)
                b0[nt][kk] = *(const half8*)&Xl[nt*16 + m16][kk*32 + quad*8];
#pragma unroll
        for (int mt = 0; mt < 4; ++mt)
#pragma unroll
            for (int nt = 0; nt < 4; ++nt) {
                acc[mt][nt] = __builtin_amdgcn_mfma_f32_16x16x32_f16(a0[mt][0], b0[nt][0], acc[mt][nt], 0, 0, 0);
                acc[mt][nt] = __builtin_amdgcn_mfma_f32_16x16x32_f16(a0[mt][1], b0[nt][1], acc[mt][nt], 0, 0, 0);
            }
#pragma unroll
        for (int j8 = 0; j8 < 8; ++j8) {
            int jl = j8*8;
            half8 w0 = *(const half8*)&Pl[t + 0][jl];
            half8 w1 = *(const half8*)&Pl[t + 1][jl];
            half8 w2 = *(const half8*)&Pl[t + 2][jl];
            half8 w3 = *(const half8*)&Pl[t + 3][jl];
            half8 w4 = *(const half8*)&Pl[t + 4][jl];
            half8 win = w0 + w1 + w2 + w3 + w4;
            union { uint4 v4; f16 h[8]; } rw; rw.v4 = raw8[j8];
#pragma unroll
            for (int e = 0; e < 8; ++e) {
                int j = kc + jl + e;
                float Bv = __expf((float)rw.h[e] - cmS[j]) * ciS[j];
                vacc = fmaf((float)win[e], Bv, vacc);
            }
        }
        __syncthreads();
    }
    Vs[t] = vacc;
    __syncthreads();
#pragma unroll
    for (int mt = 0; mt < 4; ++mt) {
        int i0 = wv*64 + mt*16 + quad*4;
        float v4[4];
        *(float4*)v4 = *(const float4*)&Vs[i0];
        float tv[4];
#pragma unroll
        for (int r = 0; r < 4; ++r) tv[r] = tanhf(5.f*v4[r]);
#pragma unroll
        for (int nt = 0; nt < 4; ++nt) {
            int c = nt*16 + m16;
            size_t base = (((size_t)(b*64 + c)*128 + h) << 8) + i0;
            float xp4[4]; *(float4*)xp4 = *(const float4*)&xP[base];
            float o4[4];
#pragma unroll
            for (int r = 0; r < 4; ++r)
                o4[r] = xp4[r]*(1.f - tv[r]) + acc[mt][nt][r]*tv[r];
            *(float4*)&outp[base] = *(float4*)o4;
        }
    }
}

// ---------------------------------------------------------------------------
extern "C" void kernel_launch(void* const* d_in, const int* in_sizes, int n_in,
                              void* d_out, int out_size, void* d_ws, size_t ws_size,
                              hipStream_t stream)
{
    const float* x_left  = (const float*)d_in[0];
    const float* x_right = (const float*)d_in[1];
    const float* conv1_w = (const float*)d_in[2];
    const float* conv1_b = (const float*)d_in[3];
    const float* conv2_w = (const float*)d_in[4];
    const float* conv2_b = (const float*)d_in[5];
    const float* bn_g    = (const float*)d_in[6];
    const float* bn_b    = (const float*)d_in[7];
    const float* bn_m    = (const float*)d_in[8];
    const float* bn_v    = (const float*)d_in[9];
    const float* rb_w1   = (const float*)d_in[10];
    const float* rb_b1   = (const float*)d_in[11];
    const float* rb_w2   = (const float*)d_in[12];
    const float* rb_b2   = (const float*)d_in[13];
    const float* bq_w    = (const float*)d_in[14];
    const float* bs_w    = (const float*)d_in[16];

    f16* W16 = (f16*)d_ws;
    f16* u  = W16;                       // 16,777,216 els
    f16* y1 = W16 + 16777216;            // 16,777,216
    f16* r  = W16 + 33554432;            // 16,777,216
    f16* S  = W16;                       // 33,554,432 (aliases u+y1)
    f16* ST = W16 + 33554432;            // 33,554,432 (aliases r + fresh)
    f16* Qh = W16 + 67108864;            //  8,388,608
    f16* Kh = W16 + 75497472;            //  8,388,608
    float* F32  = (float*)(W16 + 83886080);
    float* rmax  = F32;                  // 131,072
    float* rsumi = F32 + 131072;
    float* cmax  = F32 + 262144;         // 131,072
    float* csumi = F32 + 393216;         // 131,072
    f16* Wp1 = W16 + 84934656;           // 36,864 els (prepped rb_w1)
    f16* Wp2 = W16 + 84971520;           // 36,864 els (prepped rb_w2)

    float* out_left  = (float*)d_out;
    float* out_right = (float*)d_out + 8388608;

    // ---- weight prep (once per launch) ----
    k_wprep<<<dim3(4, 2), 256, 0, stream>>>(rb_w1, rb_w2, Wp1, Wp2);

    // ---- left branch -> Q ----
    k_catbn_m<<<NN, 256, 0, stream>>>(x_left, conv1_w, conv1_b, bn_g, bn_b, bn_m, bn_v, u);
    k_conv3r<true,  false><<<dim3(128, 4, 2), 256, 0, stream>>>(u, Wp1, rb_b1, nullptr, y1);
    k_conv3r<false, true ><<<dim3(128, 4, 2), 256, 0, stream>>>(y1, Wp2, rb_b2, u, r);
    k_conv1x1m<<<dim3(NN, 2), 256, 0, stream>>>(r, bq_w, Qh);

    // ---- right branch -> K ----
    k_catbn_m<<<NN, 256, 0, stream>>>(x_right, conv2_w, conv2_b, bn_g, bn_b, bn_m, bn_v, u);
    k_conv3r<true,  false><<<dim3(128, 4, 2), 256, 0, stream>>>(u, Wp1, rb_b1, nullptr, y1);
    k_conv3r<false, true ><<<dim3(128, 4, 2), 256, 0, stream>>>(y1, Wp2, rb_b2, u, r);
    k_conv1x1m<<<dim3(NN, 2), 256, 0, stream>>>(r, bs_w, Kh);

    // ---- attention ----
    k_score<<<NN, 256, 0, stream>>>(Qh, Kh, S, ST);
    k_stats<<<NN, 256, 0, stream>>>(S, rmax, rsumi, cmax, csumi);
    k_out<<<NN, 256, 0, stream>>>(S,  rmax, rsumi, cmax, csumi, x_right, x_left,  out_left);
    k_out<<<NN, 256, 0, stream>>>(ST, cmax, csumi, rmax, rsumi, x_left,  x_right, out_right);
}